// Round 7
// baseline (1228.693 us; speedup 1.0000x reference)
//
#include <hip/hip_runtime.h>
#include <hip/hip_cooperative_groups.h>

#define LSEQ 384
#define BATCH 32
#define BIGV 1e30f
#define TB_STK 448
#define NN ((size_t)LSEQ * LSEQ)
#define BT 32          // tile size
#define NT 12          // tiles per side
#define PIT 33         // LDS pitch

namespace cg = cooperative_groups;

__device__ __forceinline__ int detect_mmode_wave(const unsigned char* m0, int lane) {
    unsigned char v = m0[lane & 63];
    unsigned long long big = __ballot(v >= 2);
    unsigned long long off = __ballot((((lane & 63) & 3) != 0) && (v != 0));
    return big ? 2 : (off ? 1 : 0);
}
__device__ __forceinline__ bool mask_read(const void* mask, size_t idx, int mmode) {
    if (mmode == 0) return ((const unsigned int*)mask)[idx] != 0;
    if (mmode == 1) return ((const unsigned char*)mask)[idx] != 0;
    return ((const unsigned short*)mask)[idx] != 0;
}
__device__ __forceinline__ void choice_write(void* mask, size_t idx, int c, int mmode) {
    if (mmode == 0) ((unsigned int*)mask)[idx] = (unsigned int)c;
    else if (mmode == 1) ((unsigned char*)mask)[idx] = (unsigned char)c;
    else ((unsigned short*)mask)[idx] = (unsigned short)c;
}

// Fixed-length branchless edge reduction (R2-verified): min over kk in [0,32)
// of rowp[kk] + colp[kk*PIT]; out-of-range terms >= 1e30 via BIGV prefill ->
// never win or tie -> bitwise identical to the ranged version.
__device__ __forceinline__ float edge_min32(const float* rowp, const float* colp) {
    float a0 = BIGV, a1 = BIGV, a2 = BIGV, a3 = BIGV;
    #pragma unroll
    for (int kk = 0; kk < 32; kk += 4) {
        float r0 = rowp[kk], r1 = rowp[kk + 1], r2 = rowp[kk + 2], r3 = rowp[kk + 3];
        const float* cb = colp + kk * PIT;
        float c0 = cb[0], c1 = cb[PIT], c2 = cb[2 * PIT], c3 = cb[3 * PIT];
        a0 = fminf(a0, r0 + c0); a1 = fminf(a1, r1 + c1);
        a2 = fminf(a2, r2 + c2); a3 = fminf(a3, r3 + c3);
    }
    return fminf(fminf(a0, a1), fminf(a2, a3));
}

// Min-plus of <=2 middle panels, 4-wave split (R6-verified, term-identical
// to R2's far-init): wave w handles M=fm[w>>1], kq range (w&1)*4..+3.
__device__ __forceinline__ void minplus_waves(
    const float* __restrict__ dpG, int I, int J, const int* fm, int nfm,
    int wv, int lane, float part[4][BT][PIT])
{
    const int r0 = (lane >> 3) << 2, c0 = (lane & 7) << 2;
    float r16[16];
    #pragma unroll
    for (int z = 0; z < 16; ++z) r16[z] = BIGV;
    const int mi = wv >> 1, kqB = (wv & 1) * 4;
    if (mi < nfm) {
        const int M = fm[mi];
        #pragma unroll
        for (int q = 0; q < 4; ++q) {
            const int k = M * BT + (kqB + q) * 4;
            float4 a0 = *(const float4*)&dpG[(size_t)(I * BT + r0 + 0) * LSEQ + k];
            float4 a1 = *(const float4*)&dpG[(size_t)(I * BT + r0 + 1) * LSEQ + k];
            float4 a2 = *(const float4*)&dpG[(size_t)(I * BT + r0 + 2) * LSEQ + k];
            float4 a3 = *(const float4*)&dpG[(size_t)(I * BT + r0 + 3) * LSEQ + k];
            float4 b0 = *(const float4*)&dpG[(size_t)(J * BT + c0 + 0) * LSEQ + k];
            float4 b1 = *(const float4*)&dpG[(size_t)(J * BT + c0 + 1) * LSEQ + k];
            float4 b2 = *(const float4*)&dpG[(size_t)(J * BT + c0 + 2) * LSEQ + k];
            float4 b3 = *(const float4*)&dpG[(size_t)(J * BT + c0 + 3) * LSEQ + k];
            #pragma unroll
            for (int ri = 0; ri < 4; ++ri) {
                float4 av = ri == 0 ? a0 : ri == 1 ? a1 : ri == 2 ? a2 : a3;
                #pragma unroll
                for (int ci = 0; ci < 4; ++ci) {
                    float4 bv = ci == 0 ? b0 : ci == 1 ? b1 : ci == 2 ? b2 : b3;
                    float m = fminf(fminf(av.x + bv.x, av.y + bv.y),
                                    fminf(av.z + bv.z, av.w + bv.w));
                    r16[ri * 4 + ci] = fminf(r16[ri * 4 + ci], m);
                }
            }
        }
    }
    #pragma unroll
    for (int ri = 0; ri < 4; ++ri)
        #pragma unroll
        for (int ci = 0; ci < 4; ++ci)
            part[wv][r0 + ri][c0 + ci] = r16[ri * 4 + ci];
}

// acc tile base offsets for s>=4 (counts 12-s): 36 tiles per batch.
__device__ __constant__ int c_sb4[12] = {0,0,0,0, 0, 8, 15, 21, 26, 30, 33, 35};
// update-item counts per phase p: tiles with p+1 <= s <= min(2p-2,11).
__device__ __constant__ int c_updC[12] = {0, 0, 0, 8, 13, 15, 14, 10, 6, 3, 1, 0};

// ---------- cooperative DP: all 12 phases in ONE dispatch.
// grid.sync() between phases = agent-scope release/acquire (L2 wb/inv of
// dirty lines) without host launch overhead. Per-item math is R6's
// diag/sweep/update code verbatim; within-phase writer-disjointness proofs
// carry over unchanged (one writer per dp/choice row per phase).
__global__ __launch_bounds__(256, 3) void dp_coop(
    float* __restrict__ e_pair, const float* __restrict__ e_unp,
    void* mask, float* __restrict__ acc)
{
    cg::grid_group grid = cg::this_grid();

    __shared__ float dTI[BT + 1][PIT], dTJ[BT + 1][PIT];
    __shared__ float cur[BT + 1][PIT];
    __shared__ float epm[BT][PIT];
    __shared__ float part[4][BT][PIT];
    __shared__ float brow[BT], bcol[BT], s_eI[BT], s_eJ[BT];
    __shared__ float bcorn;

    const int tid = threadIdx.x, lane = tid & 63, wv = tid >> 6;
    const int mmode = detect_mmode_wave((const unsigned char*)mask, lane);

    // ---------------- phase 0: 384 diagonal tiles ----------------
    for (int it = blockIdx.x; it < BATCH * NT; it += gridDim.x) {
        const int b = it % BATCH, t = it / BATCH;
        float* dpG = e_pair + (size_t)b * NN;
        const size_t mb = (size_t)b * NN;

        for (int z = tid; z < (BT + 1) * PIT; z += 256) ((float*)dTI)[z] = BIGV;
        __syncthreads();
        if (tid < BT) {
            int i = t * BT + tid;
            float v = e_unp[b * LSEQ + i];
            s_eI[tid] = v;
            dTI[tid][tid] = v;                             // dp[i][i]
            dpG[(size_t)i * LSEQ + i] = v;
            if (i > 0) dpG[(size_t)i * LSEQ + i - 1] = v;  // mirror
        }
        for (int z = tid; z < BT * BT; z += 256) {         // stage masked energies
            int li = z >> 5, lj = z & 31;
            int i = t * BT + li, j = t * BT + lj;
            bool ok = (lj - li > 4) && mask_read(mask, mb + (size_t)i * LSEQ + j, mmode);
            epm[li][lj] = ok ? dpG[(size_t)i * LSEQ + j] : BIGV;
        }
        __syncthreads();
        if (wv == 0) {
            const int idx = lane >> 1, h = lane & 1;
            for (int sg = 1; sg < BT; ++sg) {
                const int nc = BT - sg;
                const bool act = idx < nc;
                const int li = idx, lj = idx + sg;
                const int ljc = lj < BT ? lj : BT - 1;
                const int i = t * BT + li, j = t * BT + lj;
                float ev = edge_min32(&dTI[li][0], &dTI[1][ljc]);
                float e1 = BIGV, opt0 = 0.f, x1 = BIGV, x2 = BIGV;
                if (act) {
                    if (h == 0) {
                        e1 = ev;                   // includes opt0(kk=li), opt1(kk=lj-1)
                        opt0 = dTI[li + 1][lj] + s_eI[li];
                    } else {
                        x1 = dTI[li][lj - 1] + s_eI[lj];
                        float pe = epm[li][lj];
                        if (pe < BIGV) x2 = dTI[li + 1][lj - 1] + pe;
                    }
                }
                float y1 = __shfl_xor(x1, 1), y2 = __shfl_xor(x2, 1);
                if (act && h == 0) {
                    float best = fminf(e1, y2);
                    int cch = (best == opt0) ? 0 : (best == y1) ? 1
                             : (best == y2 && y2 < BIGV) ? 2 : 3;
                    dTI[li][lj] = best;
                    dpG[(size_t)i * LSEQ + j] = best;
                    if (i > 0) dpG[(size_t)j * LSEQ + i - 1] = best;
                    choice_write(mask, mb + (size_t)j * LSEQ + i, cch, mmode);
                }
            }
        }
        __syncthreads();
    }
    grid.sync();

    // ---------------- phases p = 1..11 ----------------
    for (int p = 1; p < NT; ++p) {
        const int nswp = NT - p;
        const int tot = BATCH * (nswp + c_updC[p]);
        for (int it = blockIdx.x; it < tot; it += gridDim.x) {
            const int b = it % BATCH;
            const int u = it / BATCH;
            float* dpG = e_pair + (size_t)b * NN;
            const size_t mb = (size_t)b * NN;

            if (u >= nswp) {
                // ---------------- update role ----------------
                int e = u - nswp, s2 = p + 1;
                while (s2 < NT && e >= NT - s2) { e -= NT - s2; ++s2; }
                const int I = e, J = I + s2;
                int fm[2]; fm[0] = I + p - 1; int nfm = 1;
                if (J - (p - 1) != fm[0]) fm[nfm++] = J - (p - 1);
                minplus_waves(dpG, I, J, fm, nfm, wv, lane, part);
                __syncthreads();
                float* accT = acc + ((size_t)(b * 36 + c_sb4[s2] + I) << 10);
                const bool first = (p == (s2 + 1) / 2 + 1);
                for (int z = tid; z < BT * BT; z += 256) {
                    int li = z >> 5, lj = z & 31;
                    float m = fminf(fminf(part[0][li][lj], part[1][li][lj]),
                                    fminf(part[2][li][lj], part[3][li][lj]));
                    accT[z] = first ? m : fminf(accT[z], m);
                }
                __syncthreads();            // part reused by next item
                continue;
            }

            // ---------------- sweep role: tile (I, J = I+p) ----------------
            const int I = u, J = I + p, s = p;

            for (int z = tid; z < BT * BT; z += 256) {     // diag tiles, lower->BIGV
                int li = z >> 5, lj = z & 31;
                dTI[li][lj] = (lj >= li) ? dpG[(size_t)(I * BT + li) * LSEQ + I * BT + lj] : BIGV;
                dTJ[li][lj] = (lj >= li) ? dpG[(size_t)(J * BT + li) * LSEQ + J * BT + lj] : BIGV;
            }
            for (int z = tid; z < PIT; z += 256) {         // pad rows
                dTI[BT][z] = BIGV; dTJ[BT][z] = BIGV; cur[BT][z] = BIGV;
            }
            if (tid < BT) {
                brow[tid] = dpG[(size_t)((I + 1) * BT) * LSEQ + J * BT + tid];
                s_eI[tid] = e_unp[b * LSEQ + I * BT + tid];
            } else if (tid < 2 * BT) {
                int q = tid - BT;
                bcol[q] = dpG[(size_t)(I * BT + q) * LSEQ + J * BT - 1];
                s_eJ[q] = e_unp[b * LSEQ + J * BT + q];
            } else if (tid == 2 * BT) {
                bcorn = (s >= 2) ? dpG[(size_t)((I + 1) * BT) * LSEQ + J * BT - 1] : BIGV;
            }
            for (int z = tid; z < BT * BT; z += 256) {     // masked energies (own tile)
                int li = z >> 5, lj = z & 31;
                int i = I * BT + li, j = J * BT + lj;
                bool ok = (j - i > 4) && mask_read(mask, mb + (size_t)i * LSEQ + j, mmode);
                epm[li][lj] = ok ? dpG[(size_t)i * LSEQ + j] : BIGV;
            }

            // fresh far-init pairs (M = I+1, J-1); M in [I+2,J-2] comes from acc
            int fm[2]; int nfm = 0;
            if (s >= 2) fm[nfm++] = I + 1;
            if (s >= 3) fm[nfm++] = J - 1;
            minplus_waves(dpG, I, J, fm, nfm, wv, lane, part);
            __syncthreads();

            const float* accT = acc + ((size_t)(b * 36 + c_sb4[s] + I) << 10);
            for (int z = tid; z < BT * BT; z += 256) {
                int li = z >> 5, lj = z & 31;
                float m = fminf(fminf(part[0][li][lj], part[1][li][lj]),
                                fminf(part[2][li][lj], part[3][li][lj]));
                if (s >= 4) m = fminf(m, accT[z]);
                cur[li][lj] = m;
            }
            __syncthreads();

            if (wv == 0) {   // wave 0 sweeps (R2-verified term set)
                const int idx = lane >> 1, h = lane & 1;
                for (int sg = -(BT - 1); sg <= BT - 1; ++sg) {
                    const int asg = sg < 0 ? -sg : sg;
                    const int nc = BT - asg;
                    const bool act = idx < nc;
                    const int li = (sg >= 0) ? idx : idx - sg;
                    const int lj = li + sg;
                    const int lic = li < BT ? li : BT - 1;
                    const int ljc = (lj < BT ? (lj >= 0 ? lj : 0) : BT - 1);
                    const int i = I * BT + li, j = J * BT + lj;
                    const float* rowp = (h == 0) ? &dTI[lic][0] : &cur[lic][0];
                    const float* colp = (h == 0) ? &cur[1][ljc] : &dTJ[1][ljc];
                    float ev = edge_min32(rowp, colp);
                    float e1 = BIGV, opt0 = 0.f, farv = BIGV;
                    float x0 = BIGV, x1 = BIGV, x2 = BIGV;
                    if (act) {
                        if (h == 0) {
                            e1 = fminf(ev, dTI[li][BT - 1] + brow[lj]);
                            opt0 = ((li + 1 < BT) ? cur[li + 1][lj] : brow[lj]) + s_eI[li];
                            farv = cur[li][lj];
                        } else {
                            x0 = ev;
                            x1 = ((lj >= 1) ? cur[li][lj - 1] : bcol[li]) + s_eJ[lj];
                            float pe = epm[li][lj];
                            if (pe < BIGV) {
                                float inner = (li + 1 < BT)
                                    ? ((lj >= 1) ? cur[li + 1][lj - 1] : bcol[li + 1])
                                    : ((lj >= 1) ? brow[lj - 1] : bcorn);
                                x2 = inner + pe;
                            }
                        }
                    }
                    float y0 = __shfl_xor(x0, 1), y1 = __shfl_xor(x1, 1), y2 = __shfl_xor(x2, 1);
                    if (act && h == 0) {
                        float best = fminf(fminf(fminf(e1, y0), farv), y2);
                        int cch = (best == opt0) ? 0 : (best == y1) ? 1
                                 : (best == y2 && y2 < BIGV) ? 2 : 3;
                        cur[li][lj] = best;
                        dpG[(size_t)i * LSEQ + j] = best;
                        if (i > 0) dpG[(size_t)j * LSEQ + i - 1] = best;
                        choice_write(mask, mb + (size_t)j * LSEQ + i, cch, mmode);
                    }
                }
            }
            __syncthreads();               // LDS reused by next item
        }
        grid.sync();
    }
}

// Traceback (R3/R6-proven): 8 waves stage choices into LDS, wave 0 traverses
// barrier-free with the interval cached in registers.
__global__ __launch_bounds__(512) void tb_kernel(
    const float* __restrict__ e_pair, const void* mask, float* __restrict__ out)
{
    const int b = blockIdx.x;
    const int tid = threadIdx.x;
    const int lane = tid & 63, wv = tid >> 6;
    const float* dp = e_pair + (size_t)b * NN;
    const size_t mb = (size_t)b * NN;
    const int mmode = detect_mmode_wave((const unsigned char*)mask, lane);

    __shared__ __align__(16) unsigned char ch[LSEQ * LSEQ];   // 147456 B
    __shared__ short res[LSEQ];
    __shared__ int st[TB_STK];

    if (mmode == 1) {
        const uint4* src = (const uint4*)((const unsigned char*)mask + mb);
        for (int z = tid; z < (int)(NN / 16); z += 512) ((uint4*)ch)[z] = src[z];
    } else if (mmode == 2) {
        const uint4* src = (const uint4*)((const unsigned char*)mask + mb * 2);
        for (int z = tid; z < (int)(NN / 8); z += 512) {
            uint4 v = src[z];
            unsigned int lo = (v.x & 0xFFu) | (((v.x >> 16) & 0xFFu) << 8)
                            | ((v.y & 0xFFu) << 16) | (((v.y >> 16) & 0xFFu) << 24);
            unsigned int hi = (v.z & 0xFFu) | (((v.z >> 16) & 0xFFu) << 8)
                            | ((v.w & 0xFFu) << 16) | (((v.w >> 16) & 0xFFu) << 24);
            ((unsigned int*)ch)[z * 2] = lo;
            ((unsigned int*)ch)[z * 2 + 1] = hi;
        }
    } else {
        const uint4* src = (const uint4*)((const unsigned char*)mask + mb * 4);
        for (int z = tid; z < (int)(NN / 4); z += 512) {
            uint4 v = src[z];
            ((unsigned int*)ch)[z] = (v.x & 0xFFu) | ((v.y & 0xFFu) << 8)
                                   | ((v.z & 0xFFu) << 16) | ((v.w & 0xFFu) << 24);
        }
    }
    for (int l = tid; l < LSEQ; l += 512) res[l] = -1;
    __syncthreads();
    if (wv != 0) return;   // wave 0 traverses alone

    int sp = 0;
    int ci = 0, cj = LSEQ - 1;
    int have = 1;
    for (int iter = 0; iter < 8192; ++iter) {
        if (!have) {
            if (sp == 0) break;
            --sp;
            int pk = st[sp];
            ci = pk >> 16; cj = pk & 0xFFFF;
        }
        have = 0;
        if (ci >= cj) continue;
        int c = ch[(size_t)cj * LSEQ + ci];
        if (c == 0) { ++ci; have = 1; }
        else if (c == 1) { --cj; have = 1; }
        else if (c == 2) {
            res[ci] = (short)cj; res[cj] = (short)ci;
            if (ci + 1 <= cj - 1) { ++ci; --cj; have = 1; }
        } else {
            const int d = cj - ci;
            const float* rowi = dp + (size_t)ci * LSEQ;
            const float* mrow = dp + (size_t)cj * LSEQ;
            float bv = BIGV; int bt = d;
            for (int t = lane; t < d; t += 64) {
                float cc = rowi[ci + t] + mrow[ci + t];
                if (cc < bv || (cc == bv && t < bt)) { bv = cc; bt = t; }
            }
            for (int m = 32; m > 0; m >>= 1) {
                float ov = __shfl_xor(bv, m, 64);
                int   ot = __shfl_xor(bt, m, 64);
                if (ov < bv || (ov == bv && ot < bt)) { bv = ov; bt = ot; }
            }
            int k = ci + bt;
            if (sp < TB_STK - 1) { st[sp] = ((k + 1) << 16) | cj; ++sp; }
            cj = k; have = 1;   // process (ci, k) next
        }
    }

    for (int l = lane; l < LSEQ; l += 64)
        out[b * LSEQ + l] = (float)res[l];
    if (lane == 0)
        out[BATCH * LSEQ + b] = dp[LSEQ - 1];
}

extern "C" void kernel_launch(void* const* d_in, const int* in_sizes, int n_in,
                              void* d_out, int out_size, void* d_ws, size_t ws_size,
                              hipStream_t stream) {
    float* e_pair = (float*)d_in[0];
    const float* e_unp = (const float*)d_in[1];
    void* mask = d_in[2];
    float* acc = (float*)d_ws;   // 32 batches x 36 tiles x 1024 floats = 4.72 MB
    (void)ws_size;

    // Grid: cover the largest phase (704 items at p=5) in one round if
    // co-residency allows; clamp to the occupancy-guaranteed capacity so
    // the cooperative launch can never deadlock or be rejected for size.
    int mpc = 0;
    if (hipOccupancyMaxActiveBlocksPerMultiprocessor(&mpc, dp_coop, 256, 0)
            != hipSuccess || mpc < 1)
        mpc = 2;                                   // conservative fallback
    int grid = mpc * 256;                          // 256 CUs on MI355X
    if (grid > 704) grid = 704;

    void* args[] = { (void*)&e_pair, (void*)&e_unp, (void*)&mask, (void*)&acc };
    hipLaunchCooperativeKernel((void*)dp_coop, dim3(grid), dim3(256),
                               args, 0, stream);
    tb_kernel<<<BATCH, 512, 0, stream>>>(e_pair, mask, (float*)d_out);
}

// Round 9
// 1028.830 us; speedup vs baseline: 1.1943x; 1.1943x over previous
//
#include <hip/hip_runtime.h>

#define LSEQ 384
#define BATCH 32
#define BIGV 1e30f
#define TB_STK 448
#define NN ((size_t)LSEQ * LSEQ)
#define BT 32          // tile size
#define NT 12          // tiles per side
#define PIT 33         // LDS pitch
#define TRI_SZ 73536   // lower-triangle bytes: 384*383/2

__device__ __forceinline__ int detect_mmode_wave(const unsigned char* m0, int lane) {
    unsigned char v = m0[lane & 63];
    unsigned long long big = __ballot(v >= 2);
    unsigned long long off = __ballot((((lane & 63) & 3) != 0) && (v != 0));
    return big ? 2 : (off ? 1 : 0);
}
__device__ __forceinline__ bool mask_read(const void* mask, size_t idx, int mmode) {
    if (mmode == 0) return ((const unsigned int*)mask)[idx] != 0;
    if (mmode == 1) return ((const unsigned char*)mask)[idx] != 0;
    return ((const unsigned short*)mask)[idx] != 0;
}
__device__ __forceinline__ void choice_write(void* mask, size_t idx, int c, int mmode) {
    if (mmode == 0) ((unsigned int*)mask)[idx] = (unsigned int)c;
    else if (mmode == 1) ((unsigned char*)mask)[idx] = (unsigned char)c;
    else ((unsigned short*)mask)[idx] = (unsigned short)c;
}

// Fixed-length branchless edge reduction (R2-verified): min over kk in [0,32)
// of rowp[kk] + colp[kk*PIT]; out-of-range terms >= 1e30 via BIGV prefill ->
// never win or tie -> bitwise identical to the ranged version.
__device__ __forceinline__ float edge_min32(const float* rowp, const float* colp) {
    float a0 = BIGV, a1 = BIGV, a2 = BIGV, a3 = BIGV;
    #pragma unroll
    for (int kk = 0; kk < 32; kk += 4) {
        float r0 = rowp[kk], r1 = rowp[kk + 1], r2 = rowp[kk + 2], r3 = rowp[kk + 3];
        const float* cb = colp + kk * PIT;
        float c0 = cb[0], c1 = cb[PIT], c2 = cb[2 * PIT], c3 = cb[3 * PIT];
        a0 = fminf(a0, r0 + c0); a1 = fminf(a1, r1 + c1);
        a2 = fminf(a2, r2 + c2); a3 = fminf(a3, r3 + c3);
    }
    return fminf(fminf(a0, a1), fminf(a2, a3));
}

// Min-plus of <=2 middle panels, 4-wave split (R6-verified, term-identical
// to R2's far-init): wave w handles M=fm[w>>1], kq range (w&1)*4..+3.
__device__ __forceinline__ void minplus_waves(
    const float* __restrict__ dpG, int I, int J, const int* fm, int nfm,
    int wv, int lane, float part[4][BT][PIT])
{
    const int r0 = (lane >> 3) << 2, c0 = (lane & 7) << 2;
    float r16[16];
    #pragma unroll
    for (int z = 0; z < 16; ++z) r16[z] = BIGV;
    const int mi = wv >> 1, kqB = (wv & 1) * 4;
    if (mi < nfm) {
        const int M = fm[mi];
        #pragma unroll
        for (int q = 0; q < 4; ++q) {
            const int k = M * BT + (kqB + q) * 4;
            float4 a0 = *(const float4*)&dpG[(size_t)(I * BT + r0 + 0) * LSEQ + k];
            float4 a1 = *(const float4*)&dpG[(size_t)(I * BT + r0 + 1) * LSEQ + k];
            float4 a2 = *(const float4*)&dpG[(size_t)(I * BT + r0 + 2) * LSEQ + k];
            float4 a3 = *(const float4*)&dpG[(size_t)(I * BT + r0 + 3) * LSEQ + k];
            float4 b0 = *(const float4*)&dpG[(size_t)(J * BT + c0 + 0) * LSEQ + k];
            float4 b1 = *(const float4*)&dpG[(size_t)(J * BT + c0 + 1) * LSEQ + k];
            float4 b2 = *(const float4*)&dpG[(size_t)(J * BT + c0 + 2) * LSEQ + k];
            float4 b3 = *(const float4*)&dpG[(size_t)(J * BT + c0 + 3) * LSEQ + k];
            #pragma unroll
            for (int ri = 0; ri < 4; ++ri) {
                float4 av = ri == 0 ? a0 : ri == 1 ? a1 : ri == 2 ? a2 : a3;
                #pragma unroll
                for (int ci = 0; ci < 4; ++ci) {
                    float4 bv = ci == 0 ? b0 : ci == 1 ? b1 : ci == 2 ? b2 : b3;
                    float m = fminf(fminf(av.x + bv.x, av.y + bv.y),
                                    fminf(av.z + bv.z, av.w + bv.w));
                    r16[ri * 4 + ci] = fminf(r16[ri * 4 + ci], m);
                }
            }
        }
    }
    #pragma unroll
    for (int ri = 0; ri < 4; ++ri)
        #pragma unroll
        for (int ci = 0; ci < 4; ++ci)
            part[wv][r0 + ri][c0 + ci] = r16[ri * 4 + ci];
}

// acc tile base offsets for s>=4 (counts 12-s): 36 tiles per batch.
__device__ __constant__ int c_sb4[12] = {0,0,0,0, 0, 8, 15, 21, 26, 30, 33, 35};

// ---------- phase 0: one block (1 wave) per diagonal tile (R2/R6-proven) ----------
__global__ __launch_bounds__(64) void diag_kernel(
    float* __restrict__ e_pair, const float* __restrict__ e_unp, void* mask)
{
    __shared__ float dT[BT + 1][PIT];
    __shared__ float epm[BT][PIT];
    __shared__ float s_eunp[BT];

    const int bid = blockIdx.x;
    const int b = bid / NT, t = bid % NT;
    const int lane = threadIdx.x;
    float* dpG = e_pair + (size_t)b * NN;
    const size_t mb = (size_t)b * NN;
    const int mmode = detect_mmode_wave((const unsigned char*)mask, lane);

    for (int z = lane; z < (BT + 1) * PIT; z += 64) ((float*)dT)[z] = BIGV;
    __syncthreads();
    if (lane < BT) {
        int i = t * BT + lane;
        float v = e_unp[b * LSEQ + i];
        s_eunp[lane] = v;
        dT[lane][lane] = v;
        dpG[(size_t)i * LSEQ + i] = v;
        if (i > 0) dpG[(size_t)i * LSEQ + i - 1] = v;  // mirror
    }
    for (int z = lane; z < BT * BT; z += 64) {
        int li = z >> 5, lj = z & 31;
        int i = t * BT + li, j = t * BT + lj;
        bool ok = (lj - li > 4) && mask_read(mask, mb + (size_t)i * LSEQ + j, mmode);
        epm[li][lj] = ok ? dpG[(size_t)i * LSEQ + j] : BIGV;
    }
    __syncthreads();

    const int idx = lane >> 1, h = lane & 1;
    for (int sg = 1; sg < BT; ++sg) {
        const int nc = BT - sg;
        const bool act = idx < nc;
        const int li = idx, lj = idx + sg;
        const int ljc = lj < BT ? lj : BT - 1;
        const int i = t * BT + li, j = t * BT + lj;
        float ev = edge_min32(&dT[li][0], &dT[1][ljc]);
        float e1 = BIGV, opt0 = 0.f, x1 = BIGV, x2 = BIGV;
        if (act) {
            if (h == 0) {
                e1 = ev;
                opt0 = dT[li + 1][lj] + s_eunp[li];
            } else {
                x1 = dT[li][lj - 1] + s_eunp[lj];
                float pe = epm[li][lj];
                if (pe < BIGV) x2 = dT[li + 1][lj - 1] + pe;
            }
        }
        float y1 = __shfl_xor(x1, 1), y2 = __shfl_xor(x2, 1);
        if (act && h == 0) {
            float best = fminf(e1, y2);
            int cch = (best == opt0) ? 0 : (best == y1) ? 1
                     : (best == y2 && y2 < BIGV) ? 2 : 3;
            dT[li][lj] = best;
            dpG[(size_t)i * LSEQ + j] = best;
            if (i > 0) dpG[(size_t)j * LSEQ + i - 1] = best;
            choice_write(mask, mb + (size_t)j * LSEQ + i, cch, mmode);
        }
    }
}

// ---------- dispatches p=1..8 (R6-proven, verbatim) ----------
__global__ __launch_bounds__(256) void step_kernel(
    float* __restrict__ e_pair, const float* __restrict__ e_unp,
    void* mask, float* __restrict__ acc, int p)
{
    __shared__ float dTI[BT + 1][PIT], dTJ[BT + 1][PIT];
    __shared__ float cur[BT + 1][PIT];
    __shared__ float epm[BT][PIT];
    __shared__ float part[4][BT][PIT];
    __shared__ float brow[BT], bcol[BT], s_eI[BT], s_eJ[BT];
    __shared__ float bcorn;

    const int b = blockIdx.x % BATCH;
    const int u = blockIdx.x / BATCH;
    const int nswp = NT - p;
    const int tid = threadIdx.x, lane = tid & 63, wv = tid >> 6;
    float* dpG = e_pair + (size_t)b * NN;
    const size_t mb = (size_t)b * NN;

    if (u >= nswp) {
        // update role: pre-accumulate far-init pairs for future tiles
        int e = u - nswp, s2 = p + 1;
        while (s2 < NT && e >= NT - s2) { e -= NT - s2; ++s2; }
        const int I = e, J = I + s2;
        int fm[2]; fm[0] = I + p - 1; int nfm = 1;
        if (J - (p - 1) != fm[0]) fm[nfm++] = J - (p - 1);
        minplus_waves(dpG, I, J, fm, nfm, wv, lane, part);
        __syncthreads();
        float* accT = acc + ((size_t)(b * 36 + c_sb4[s2] + I) << 10);
        const bool first = (p == (s2 + 1) / 2 + 1);
        for (int z = tid; z < BT * BT; z += 256) {
            int li = z >> 5, lj = z & 31;
            float m = fminf(fminf(part[0][li][lj], part[1][li][lj]),
                            fminf(part[2][li][lj], part[3][li][lj]));
            accT[z] = first ? m : fminf(accT[z], m);
        }
        return;
    }

    // sweep role: tile (I, J = I+p)
    const int I = u, J = I + p, s = p;
    const int mmode = detect_mmode_wave((const unsigned char*)mask, lane);

    for (int z = tid; z < BT * BT; z += 256) {
        int li = z >> 5, lj = z & 31;
        dTI[li][lj] = (lj >= li) ? dpG[(size_t)(I * BT + li) * LSEQ + I * BT + lj] : BIGV;
        dTJ[li][lj] = (lj >= li) ? dpG[(size_t)(J * BT + li) * LSEQ + J * BT + lj] : BIGV;
    }
    for (int z = tid; z < PIT; z += 256) {
        dTI[BT][z] = BIGV; dTJ[BT][z] = BIGV; cur[BT][z] = BIGV;
    }
    if (tid < BT) {
        brow[tid] = dpG[(size_t)((I + 1) * BT) * LSEQ + J * BT + tid];
        s_eI[tid] = e_unp[b * LSEQ + I * BT + tid];
    } else if (tid < 2 * BT) {
        int q = tid - BT;
        bcol[q] = dpG[(size_t)(I * BT + q) * LSEQ + J * BT - 1];
        s_eJ[q] = e_unp[b * LSEQ + J * BT + q];
    } else if (tid == 2 * BT) {
        bcorn = (s >= 2) ? dpG[(size_t)((I + 1) * BT) * LSEQ + J * BT - 1] : BIGV;
    }
    for (int z = tid; z < BT * BT; z += 256) {
        int li = z >> 5, lj = z & 31;
        int i = I * BT + li, j = J * BT + lj;
        bool ok = (j - i > 4) && mask_read(mask, mb + (size_t)i * LSEQ + j, mmode);
        epm[li][lj] = ok ? dpG[(size_t)i * LSEQ + j] : BIGV;
    }

    int fm[2]; int nfm = 0;
    if (s >= 2) fm[nfm++] = I + 1;
    if (s >= 3) fm[nfm++] = J - 1;
    minplus_waves(dpG, I, J, fm, nfm, wv, lane, part);
    __syncthreads();

    const float* accT = acc + ((size_t)(b * 36 + c_sb4[s] + I) << 10);
    for (int z = tid; z < BT * BT; z += 256) {
        int li = z >> 5, lj = z & 31;
        float m = fminf(fminf(part[0][li][lj], part[1][li][lj]),
                        fminf(part[2][li][lj], part[3][li][lj]));
        if (s >= 4) m = fminf(m, accT[z]);
        cur[li][lj] = m;
    }
    __syncthreads();
    if (wv != 0) return;

    const int idx = lane >> 1, h = lane & 1;
    for (int sg = -(BT - 1); sg <= BT - 1; ++sg) {
        const int asg = sg < 0 ? -sg : sg;
        const int nc = BT - asg;
        const bool act = idx < nc;
        const int li = (sg >= 0) ? idx : idx - sg;
        const int lj = li + sg;
        const int lic = li < BT ? li : BT - 1;
        const int ljc = (lj < BT ? (lj >= 0 ? lj : 0) : BT - 1);
        const int i = I * BT + li, j = J * BT + lj;
        const float* rowp = (h == 0) ? &dTI[lic][0] : &cur[lic][0];
        const float* colp = (h == 0) ? &cur[1][ljc] : &dTJ[1][ljc];
        float ev = edge_min32(rowp, colp);
        float e1 = BIGV, opt0 = 0.f, farv = BIGV;
        float x0 = BIGV, x1 = BIGV, x2 = BIGV;
        if (act) {
            if (h == 0) {
                e1 = fminf(ev, dTI[li][BT - 1] + brow[lj]);
                opt0 = ((li + 1 < BT) ? cur[li + 1][lj] : brow[lj]) + s_eI[li];
                farv = cur[li][lj];
            } else {
                x0 = ev;
                x1 = ((lj >= 1) ? cur[li][lj - 1] : bcol[li]) + s_eJ[lj];
                float pe = epm[li][lj];
                if (pe < BIGV) {
                    float inner = (li + 1 < BT)
                        ? ((lj >= 1) ? cur[li + 1][lj - 1] : bcol[li + 1])
                        : ((lj >= 1) ? brow[lj - 1] : bcorn);
                    x2 = inner + pe;
                }
            }
        }
        float y0 = __shfl_xor(x0, 1), y1 = __shfl_xor(x1, 1), y2 = __shfl_xor(x2, 1);
        if (act && h == 0) {
            float best = fminf(fminf(fminf(e1, y0), farv), y2);
            int cch = (best == opt0) ? 0 : (best == y1) ? 1
                     : (best == y2 && y2 < BIGV) ? 2 : 3;
            cur[li][lj] = best;
            dpG[(size_t)i * LSEQ + j] = best;
            if (i > 0) dpG[(size_t)j * LSEQ + i - 1] = best;
            choice_write(mask, mb + (size_t)j * LSEQ + i, cch, mmode);
        }
    }
}

// ---------- fused tail: per batch, ONE block runs phases 9..11 + traceback.
// All deps are pre-entry (dispatch-boundary visible) or same-block. Choices
// of tail tiles go ONLY to LDS ch (traceback is their sole consumer).
__global__ __launch_bounds__(256) void tail_kernel(
    float* __restrict__ e_pair, const float* __restrict__ e_unp,
    void* mask, float* __restrict__ acc, float* __restrict__ out)
{
    __shared__ unsigned char ch[TRI_SZ];          // lower-tri choices, 73.5 KB
    __shared__ float dTI[BT + 1][PIT], dTJ[BT + 1][PIT];
    __shared__ float cur[BT + 1][PIT];
    __shared__ float epm[BT][PIT];
    __shared__ float part[4][BT][PIT];
    __shared__ float brow[BT], bcol[BT], s_eI[BT], s_eJ[BT];
    __shared__ float bcorn;
    __shared__ short res[LSEQ];
    __shared__ int st[TB_STK];

    const int b = blockIdx.x;
    const int tid = threadIdx.x, lane = tid & 63, wv = tid >> 6;
    float* dpG = e_pair + (size_t)b * NN;
    const size_t mb = (size_t)b * NN;
    const int mmode = detect_mmode_wave((const unsigned char*)mask, lane);

    // stage lower-triangle choice bytes (low byte of each element, LE)
    {
        const unsigned char* mbase = (const unsigned char*)mask;
        const int esz = (mmode == 0) ? 4 : (mmode == 1) ? 1 : 2;
        for (int j = wv; j < LSEQ; j += 4) {
            const size_t go = (mb + (size_t)j * LSEQ) * esz;
            const size_t lo = (size_t)j * (j - 1) / 2;
            for (int i = lane; i < j; i += 64)
                ch[lo + i] = mbase[go + (size_t)i * esz];
        }
    }
    for (int l = tid; l < LSEQ; l += 256) res[l] = -1;
    for (int z = tid; z < PIT; z += 256) {        // pad rows (persist)
        dTI[BT][z] = BIGV; dTJ[BT][z] = BIGV; cur[BT][z] = BIGV;
    }
    __syncthreads();

    // task list: role 0 = update {I, J, M0, M1}; role 1 = sweep {I, J}
    // order: upd(p=9)x3, sweeps p=9, upd(p=10), sweeps p=10, sweep p=11
    static const int tasks[10][5] = {
        {0, 0, 10, 8, 2}, {0, 1, 11, 9, 3}, {0, 0, 11, 8, 3},
        {1, 0, 9, 0, 0}, {1, 1, 10, 0, 0}, {1, 2, 11, 0, 0},
        {0, 0, 11, 9, 2},
        {1, 0, 10, 0, 0}, {1, 1, 11, 0, 0},
        {1, 0, 11, 0, 0} };

    for (int tk = 0; tk < 10; ++tk) {
        const int I = tasks[tk][1], J = tasks[tk][2], s = J - I;
        if (tasks[tk][0] == 0) {
            // ---------- update ----------
            int fm[2] = { tasks[tk][3], tasks[tk][4] };
            minplus_waves(dpG, I, J, fm, 2, wv, lane, part);
            __syncthreads();
            float* accT = acc + ((size_t)(b * 36 + c_sb4[s] + I) << 10);
            for (int z = tid; z < BT * BT; z += 256) {
                int li = z >> 5, lj = z & 31;
                float m = fminf(fminf(part[0][li][lj], part[1][li][lj]),
                                fminf(part[2][li][lj], part[3][li][lj]));
                accT[z] = fminf(accT[z], m);      // never first at p>=9
            }
            __syncthreads();
            continue;
        }
        // ---------- sweep tile (I, J) ----------
        for (int z = tid; z < BT * BT; z += 256) {
            int li = z >> 5, lj = z & 31;
            dTI[li][lj] = (lj >= li) ? dpG[(size_t)(I * BT + li) * LSEQ + I * BT + lj] : BIGV;
            dTJ[li][lj] = (lj >= li) ? dpG[(size_t)(J * BT + li) * LSEQ + J * BT + lj] : BIGV;
        }
        if (tid < BT) {
            brow[tid] = dpG[(size_t)((I + 1) * BT) * LSEQ + J * BT + tid];
            s_eI[tid] = e_unp[b * LSEQ + I * BT + tid];
        } else if (tid < 2 * BT) {
            int q = tid - BT;
            bcol[q] = dpG[(size_t)(I * BT + q) * LSEQ + J * BT - 1];
            s_eJ[q] = e_unp[b * LSEQ + J * BT + q];
        } else if (tid == 2 * BT) {
            bcorn = dpG[(size_t)((I + 1) * BT) * LSEQ + J * BT - 1];   // s>=2 always
        }
        for (int z = tid; z < BT * BT; z += 256) {
            int li = z >> 5, lj = z & 31;
            int i = I * BT + li, j = J * BT + lj;
            bool ok = (j - i > 4) && mask_read(mask, mb + (size_t)i * LSEQ + j, mmode);
            epm[li][lj] = ok ? dpG[(size_t)i * LSEQ + j] : BIGV;
        }
        int fm[2] = { I + 1, J - 1 };             // s >= 9 -> both fresh pairs
        minplus_waves(dpG, I, J, fm, 2, wv, lane, part);
        __syncthreads();
        const float* accT = acc + ((size_t)(b * 36 + c_sb4[s] + I) << 10);
        for (int z = tid; z < BT * BT; z += 256) {
            int li = z >> 5, lj = z & 31;
            float m = fminf(fminf(part[0][li][lj], part[1][li][lj]),
                            fminf(part[2][li][lj], part[3][li][lj]));
            cur[li][lj] = fminf(m, accT[z]);      // s >= 4 always
        }
        __syncthreads();
        if (wv == 0) {                             // R2-verified sweep
            const int idx = lane >> 1, h = lane & 1;
            for (int sg = -(BT - 1); sg <= BT - 1; ++sg) {
                const int asg = sg < 0 ? -sg : sg;
                const int nc = BT - asg;
                const bool act = idx < nc;
                const int li = (sg >= 0) ? idx : idx - sg;
                const int lj = li + sg;
                const int lic = li < BT ? li : BT - 1;
                const int ljc = (lj < BT ? (lj >= 0 ? lj : 0) : BT - 1);
                const int i = I * BT + li, j = J * BT + lj;
                const float* rowp = (h == 0) ? &dTI[lic][0] : &cur[lic][0];
                const float* colp = (h == 0) ? &cur[1][ljc] : &dTJ[1][ljc];
                float ev = edge_min32(rowp, colp);
                float e1 = BIGV, opt0 = 0.f, farv = BIGV;
                float x0 = BIGV, x1 = BIGV, x2 = BIGV;
                if (act) {
                    if (h == 0) {
                        e1 = fminf(ev, dTI[li][BT - 1] + brow[lj]);
                        opt0 = ((li + 1 < BT) ? cur[li + 1][lj] : brow[lj]) + s_eI[li];
                        farv = cur[li][lj];
                    } else {
                        x0 = ev;
                        x1 = ((lj >= 1) ? cur[li][lj - 1] : bcol[li]) + s_eJ[lj];
                        float pe = epm[li][lj];
                        if (pe < BIGV) {
                            float inner = (li + 1 < BT)
                                ? ((lj >= 1) ? cur[li + 1][lj - 1] : bcol[li + 1])
                                : ((lj >= 1) ? brow[lj - 1] : bcorn);
                            x2 = inner + pe;
                        }
                    }
                }
                float y0 = __shfl_xor(x0, 1), y1 = __shfl_xor(x1, 1), y2 = __shfl_xor(x2, 1);
                if (act && h == 0) {
                    float best = fminf(fminf(fminf(e1, y0), farv), y2);
                    int cch = (best == opt0) ? 0 : (best == y1) ? 1
                             : (best == y2 && y2 < BIGV) ? 2 : 3;
                    cur[li][lj] = best;
                    dpG[(size_t)i * LSEQ + j] = best;
                    if (i > 0) dpG[(size_t)j * LSEQ + i - 1] = best;
                    ch[(size_t)j * (j - 1) / 2 + i] = (unsigned char)cch;   // LDS only
                }
            }
        }
        __syncthreads();
    }

    // ---------- traceback (R3/R6-proven traversal; ch = lower-tri LDS) ----------
    if (wv == 0) {
        int sp = 0;
        int ci = 0, cj = LSEQ - 1;
        int have = 1;
        for (int iter = 0; iter < 8192; ++iter) {
            if (!have) {
                if (sp == 0) break;
                --sp;
                int pk = st[sp];
                ci = pk >> 16; cj = pk & 0xFFFF;
            }
            have = 0;
            if (ci >= cj) continue;
            int c = ch[(size_t)(cj * (cj - 1) >> 1) + ci];
            if (c == 0) { ++ci; have = 1; }
            else if (c == 1) { --cj; have = 1; }
            else if (c == 2) {
                res[ci] = (short)cj; res[cj] = (short)ci;
                if (ci + 1 <= cj - 1) { ++ci; --cj; have = 1; }
            } else {
                const int d = cj - ci;
                const float* rowi = dpG + (size_t)ci * LSEQ;
                const float* mrow = dpG + (size_t)cj * LSEQ;
                float bv = BIGV; int bt = d;
                for (int t = lane; t < d; t += 64) {
                    float cc = rowi[ci + t] + mrow[ci + t];
                    if (cc < bv || (cc == bv && t < bt)) { bv = cc; bt = t; }
                }
                for (int m = 32; m > 0; m >>= 1) {
                    float ov = __shfl_xor(bv, m, 64);
                    int   ot = __shfl_xor(bt, m, 64);
                    if (ov < bv || (ov == bv && ot < bt)) { bv = ov; bt = ot; }
                }
                int k = ci + bt;
                if (sp < TB_STK - 1) { st[sp] = ((k + 1) << 16) | cj; ++sp; }
                cj = k; have = 1;
            }
        }
        for (int l = lane; l < LSEQ; l += 64)
            out[b * LSEQ + l] = (float)res[l];
        if (lane == 0)
            out[BATCH * LSEQ + b] = dpG[LSEQ - 1];
    }
}

extern "C" void kernel_launch(void* const* d_in, const int* in_sizes, int n_in,
                              void* d_out, int out_size, void* d_ws, size_t ws_size,
                              hipStream_t stream) {
    float* e_pair = (float*)d_in[0];
    const float* e_unp = (const float*)d_in[1];
    void* mask = d_in[2];
    float* acc = (float*)d_ws;   // 32 batches x 36 tiles x 1024 floats = 4.72 MB
    (void)ws_size;

    // update-block counts per dispatch p (p<=8): tiles with p+1 <= s <= 2p-2
    static const int updC[9] = {0, 0, 0, 8, 13, 15, 14, 10, 6};

    diag_kernel<<<BATCH * NT, 64, 0, stream>>>(e_pair, e_unp, mask);
    for (int p = 1; p <= 8; ++p)
        step_kernel<<<BATCH * (NT - p + updC[p]), 256, 0, stream>>>(
            e_pair, e_unp, mask, acc, p);
    tail_kernel<<<BATCH, 256, 0, stream>>>(e_pair, e_unp, mask, acc, (float*)d_out);
}

// Round 10
// 812.990 us; speedup vs baseline: 1.5113x; 1.2655x over previous
//
#include <hip/hip_runtime.h>

#define LSEQ 384
#define BATCH 32
#define BIGV 1e30f
#define TB_STK 448
#define NN ((size_t)LSEQ * LSEQ)
#define BT 32          // tile size
#define NT 12          // tiles per side
#define PIT 33         // LDS pitch

__device__ __constant__ int c_sb4[12] = {0,0,0,0, 0, 8, 15, 21, 26, 30, 33, 35};
// update entries: {s', I, M0,M1,M2,M3, nM, first}; F_d range = [c_updS[d], ...)
__device__ __constant__ int c_updS[8] = {0,0,0,0, 9, 15, 16, 16};
__device__ __constant__ int c_upd[16][8] = {
 {7,0,3,4,0,0,2,1},{7,1,4,5,0,0,2,1},{7,2,5,6,0,0,2,1},{7,3,6,7,0,0,2,1},{7,4,7,8,0,0,2,1},
 {8,0,4,0,0,0,1,1},{8,1,5,0,0,0,1,1},{8,2,6,0,0,0,1,1},{8,3,7,0,0,0,1,1},
 {9,0,3,4,5,6,4,1},{9,1,4,5,6,7,4,1},{9,2,5,6,7,8,4,1},
 {10,0,4,5,6,0,3,1},{10,1,5,6,7,0,3,1},
 {11,0,5,6,0,0,2,1},
 {11,0,3,4,7,8,4,0}};

__device__ __forceinline__ int detect_mmode_wave(const unsigned char* m0, int lane) {
    unsigned char v = m0[lane & 63];
    unsigned long long big = __ballot(v >= 2);
    unsigned long long off = __ballot((((lane & 63) & 3) != 0) && (v != 0));
    return big ? 2 : (off ? 1 : 0);
}
__device__ __forceinline__ bool mask_read(const void* mask, size_t idx, int mmode) {
    if (mmode == 0) return ((const unsigned int*)mask)[idx] != 0;
    if (mmode == 1) return ((const unsigned char*)mask)[idx] != 0;
    return ((const unsigned short*)mask)[idx] != 0;
}
__device__ __forceinline__ void choice_write(void* mask, size_t idx, int c, int mmode) {
    if (mmode == 0) ((unsigned int*)mask)[idx] = (unsigned int)c;
    else if (mmode == 1) ((unsigned char*)mask)[idx] = (unsigned char)c;
    else ((unsigned short*)mask)[idx] = (unsigned short)c;
}

// Fixed-length branchless edge reduction (R2-verified).
__device__ __forceinline__ float edge_min32(const float* rowp, const float* colp) {
    float a0 = BIGV, a1 = BIGV, a2 = BIGV, a3 = BIGV;
    #pragma unroll
    for (int kk = 0; kk < 32; kk += 4) {
        float r0 = rowp[kk], r1 = rowp[kk + 1], r2 = rowp[kk + 2], r3 = rowp[kk + 3];
        const float* cb = colp + kk * PIT;
        float c0 = cb[0], c1 = cb[PIT], c2 = cb[2 * PIT], c3 = cb[3 * PIT];
        a0 = fminf(a0, r0 + c0); a1 = fminf(a1, r1 + c1);
        a2 = fminf(a2, r2 + c2); a3 = fminf(a3, r3 + c3);
    }
    return fminf(fminf(a0, a1), fminf(a2, a3));
}

// Fresh-M list: pairs handled in-block at sweep time (global panels).
// odd tile: dM in {1,2,s-2,s-1}; even: dM in {2,3,s-3,s-2}; keep m in [2d-3,2d-2].
__device__ __forceinline__ int fresh_list(int dd, int s, int odd, int K, int* fm) {
    int cand[4];
    if (odd) { cand[0]=1; cand[1]=2; cand[2]=s-2; cand[3]=s-1; }
    else     { cand[0]=2; cand[1]=3; cand[2]=s-3; cand[3]=s-2; }
    int n = 0;
    for (int c = 0; c < 4; ++c) {
        int dM = cand[c];
        if (dM < 1 || dM > s - 1) continue;
        int m = dM > s - dM ? dM : s - dM;
        if (m > 2*dd - 2 || m < 2*dd - 3) continue;
        bool dup = false;
        for (int q = 0; q < n; ++q) if (fm[q] == K + dM) dup = true;
        if (!dup) fm[n++] = K + dM;
    }
    return n;
}

// Min-plus over middle tiles fm[start], fm[start+stride], ... (R6 term set,
// global panels). One wave fills one slot; idle M-range -> slot = BIGV.
__device__ void minplus_slot(const float* __restrict__ dpG, int Krow, int J,
                             const int* fm, int nfm, int start, int stride,
                             int lane, float (*slot)[PIT]) {
    const int r0 = (lane >> 3) << 2, c0 = (lane & 7) << 2;
    float r16[16];
    #pragma unroll
    for (int z = 0; z < 16; ++z) r16[z] = BIGV;
    for (int mi = start; mi < nfm; mi += stride) {
        const int M = fm[mi];
        #pragma unroll
        for (int kq = 0; kq < 8; ++kq) {
            const int k = M * BT + kq * 4;
            float4 a0 = *(const float4*)&dpG[(size_t)(Krow * BT + r0 + 0) * LSEQ + k];
            float4 a1 = *(const float4*)&dpG[(size_t)(Krow * BT + r0 + 1) * LSEQ + k];
            float4 a2 = *(const float4*)&dpG[(size_t)(Krow * BT + r0 + 2) * LSEQ + k];
            float4 a3 = *(const float4*)&dpG[(size_t)(Krow * BT + r0 + 3) * LSEQ + k];
            float4 b0 = *(const float4*)&dpG[(size_t)(J * BT + c0 + 0) * LSEQ + k];
            float4 b1 = *(const float4*)&dpG[(size_t)(J * BT + c0 + 1) * LSEQ + k];
            float4 b2 = *(const float4*)&dpG[(size_t)(J * BT + c0 + 2) * LSEQ + k];
            float4 b3 = *(const float4*)&dpG[(size_t)(J * BT + c0 + 3) * LSEQ + k];
            #pragma unroll
            for (int ri = 0; ri < 4; ++ri) {
                float4 av = ri == 0 ? a0 : ri == 1 ? a1 : ri == 2 ? a2 : a3;
                #pragma unroll
                for (int ci = 0; ci < 4; ++ci) {
                    float4 bv = ci == 0 ? b0 : ci == 1 ? b1 : ci == 2 ? b2 : b3;
                    float m = fminf(fminf(av.x + bv.x, av.y + bv.y),
                                    fminf(av.z + bv.z, av.w + bv.w));
                    r16[ri * 4 + ci] = fminf(r16[ri * 4 + ci], m);
                }
            }
        }
    }
    #pragma unroll
    for (int ri = 0; ri < 4; ++ri)
        #pragma unroll
        for (int ci = 0; ci < 4; ++ci)
            slot[r0 + ri][c0 + ci] = r16[ri * 4 + ci];
}

// Pair M=I+1 for even tile: A = tile(I,I+1) (global; d==1 -> curA LDS),
// B[kk][lj] = kk<31 ? curB[kk+1][lj] : browB[lj]  (tile (I+1,J) in LDS).
__device__ void pair_via_curB(const float* __restrict__ dpG, int I, int d,
                              const float (*curA)[PIT], const float (*curB)[PIT],
                              const float* browB, int lane, float (*slot)[PIT]) {
    const int r0 = (lane >> 3) << 2, c0 = (lane & 7) << 2;
    float r16[16];
    #pragma unroll
    for (int z = 0; z < 16; ++z) r16[z] = BIGV;
    for (int kk = 0; kk < 32; ++kk) {
        float a[4], bv[4];
        #pragma unroll
        for (int ri = 0; ri < 4; ++ri)
            a[ri] = (d == 1) ? curA[r0 + ri][kk]
                  : dpG[(size_t)(I * BT + r0 + ri) * LSEQ + (I + 1) * BT + kk];
        #pragma unroll
        for (int ci = 0; ci < 4; ++ci)
            bv[ci] = (kk < 31) ? curB[kk + 1][c0 + ci] : browB[c0 + ci];
        #pragma unroll
        for (int ri = 0; ri < 4; ++ri)
            #pragma unroll
            for (int ci = 0; ci < 4; ++ci)
                r16[ri * 4 + ci] = fminf(r16[ri * 4 + ci], a[ri] + bv[ci]);
    }
    #pragma unroll
    for (int ri = 0; ri < 4; ++ri)
        #pragma unroll
        for (int ci = 0; ci < 4; ++ci)
            slot[r0 + ri][c0 + ci] = r16[ri * 4 + ci];
}

// Pair M=J-1 for even tile: A = curA (tile (I,J-1) LDS),
// B = global mirror rows tile J over cols tile J-1 (span-1/diag tiles, old).
__device__ void pair_via_curA(const float* __restrict__ dpG, int J,
                              const float (*curA)[PIT], int lane, float (*slot)[PIT]) {
    const int r0 = (lane >> 3) << 2, c0 = (lane & 7) << 2;
    float r16[16];
    #pragma unroll
    for (int z = 0; z < 16; ++z) r16[z] = BIGV;
    #pragma unroll
    for (int kq = 0; kq < 8; ++kq) {
        const int k = (J - 1) * BT + kq * 4;
        float4 b0 = *(const float4*)&dpG[(size_t)(J * BT + c0 + 0) * LSEQ + k];
        float4 b1 = *(const float4*)&dpG[(size_t)(J * BT + c0 + 1) * LSEQ + k];
        float4 b2 = *(const float4*)&dpG[(size_t)(J * BT + c0 + 2) * LSEQ + k];
        float4 b3 = *(const float4*)&dpG[(size_t)(J * BT + c0 + 3) * LSEQ + k];
        #pragma unroll
        for (int ri = 0; ri < 4; ++ri) {
            const float* ar = &curA[r0 + ri][kq * 4];
            float ax = ar[0], ay = ar[1], az = ar[2], aw = ar[3];
            #pragma unroll
            for (int ci = 0; ci < 4; ++ci) {
                float4 bv = ci == 0 ? b0 : ci == 1 ? b1 : ci == 2 ? b2 : b3;
                float m = fminf(fminf(ax + bv.x, ay + bv.y),
                                fminf(az + bv.z, aw + bv.w));
                r16[ri * 4 + ci] = fminf(r16[ri * 4 + ci], m);
            }
        }
    }
    #pragma unroll
    for (int ri = 0; ri < 4; ++ri)
        #pragma unroll
        for (int ci = 0; ci < 4; ++ci)
            slot[r0 + ri][c0 + ci] = r16[ri * 4 + ci];
}

// R2-verified in-tile sweep, executed by ONE wave. cur updated in LDS always;
// global dp/mirror/choice writes gated by dowrite.
__device__ void sweep_wave(
    const float (*dTI)[PIT], const float (*dTJ)[PIT], float (*cur)[PIT],
    const float (*epm)[PIT], const float* eI, const float* eJ,
    const float* brow, const float* bcol, float bcorn,
    int I, int J, float* __restrict__ dpG, size_t mb, void* mask, int mmode,
    int lane, int dowrite)
{
    const int idx = lane >> 1, h = lane & 1;
    for (int sg = -(BT - 1); sg <= BT - 1; ++sg) {
        const int asg = sg < 0 ? -sg : sg;
        const int nc = BT - asg;
        const bool act = idx < nc;
        const int li = (sg >= 0) ? idx : idx - sg;
        const int lj = li + sg;
        const int lic = li < BT ? li : BT - 1;
        const int ljc = (lj < BT ? (lj >= 0 ? lj : 0) : BT - 1);
        const int i = I * BT + li, j = J * BT + lj;
        const float* rowp = (h == 0) ? &dTI[lic][0] : &cur[lic][0];
        const float* colp = (h == 0) ? &cur[1][ljc] : &dTJ[1][ljc];
        float ev = edge_min32(rowp, colp);
        float e1 = BIGV, opt0 = 0.f, farv = BIGV;
        float x0 = BIGV, x1 = BIGV, x2 = BIGV;
        if (act) {
            if (h == 0) {
                e1 = fminf(ev, dTI[li][BT - 1] + brow[lj]);
                opt0 = ((li + 1 < BT) ? cur[li + 1][lj] : brow[lj]) + eI[li];
                farv = cur[li][lj];
            } else {
                x0 = ev;
                x1 = ((lj >= 1) ? cur[li][lj - 1] : bcol[li]) + eJ[lj];
                float pe = epm[li][lj];
                if (pe < BIGV) {
                    float inner = (li + 1 < BT)
                        ? ((lj >= 1) ? cur[li + 1][lj - 1] : bcol[li + 1])
                        : ((lj >= 1) ? brow[lj - 1] : bcorn);
                    x2 = inner + pe;
                }
            }
        }
        float y0 = __shfl_xor(x0, 1), y1 = __shfl_xor(x1, 1), y2 = __shfl_xor(x2, 1);
        if (act && h == 0) {
            float best = fminf(fminf(fminf(e1, y0), farv), y2);
            int cch = (best == opt0) ? 0 : (best == y1) ? 1
                     : (best == y2 && y2 < BIGV) ? 2 : 3;
            cur[li][lj] = best;
            if (dowrite) {
                dpG[(size_t)i * LSEQ + j] = best;
                if (i > 0) dpG[(size_t)j * LSEQ + i - 1] = best;
                choice_write(mask, mb + (size_t)j * LSEQ + i, cch, mmode);
            }
        }
    }
}

// ---------- phase 0: one block (1 wave) per diagonal tile (R2/R6-proven) ----------
__global__ __launch_bounds__(64) void diag_kernel(
    float* __restrict__ e_pair, const float* __restrict__ e_unp, void* mask)
{
    __shared__ float dT[BT + 1][PIT];
    __shared__ float epm[BT][PIT];
    __shared__ float s_eunp[BT];

    const int bid = blockIdx.x;
    const int b = bid / NT, t = bid % NT;
    const int lane = threadIdx.x;
    float* dpG = e_pair + (size_t)b * NN;
    const size_t mb = (size_t)b * NN;
    const int mmode = detect_mmode_wave((const unsigned char*)mask, lane);

    for (int z = lane; z < (BT + 1) * PIT; z += 64) ((float*)dT)[z] = BIGV;
    __syncthreads();
    if (lane < BT) {
        int i = t * BT + lane;
        float v = e_unp[b * LSEQ + i];
        s_eunp[lane] = v;
        dT[lane][lane] = v;
        dpG[(size_t)i * LSEQ + i] = v;
        if (i > 0) dpG[(size_t)i * LSEQ + i - 1] = v;  // mirror
    }
    for (int z = lane; z < BT * BT; z += 64) {
        int li = z >> 5, lj = z & 31;
        int i = t * BT + li, j = t * BT + lj;
        bool ok = (lj - li > 4) && mask_read(mask, mb + (size_t)i * LSEQ + j, mmode);
        epm[li][lj] = ok ? dpG[(size_t)i * LSEQ + j] : BIGV;
    }
    __syncthreads();

    const int idx = lane >> 1, h = lane & 1;
    for (int sg = 1; sg < BT; ++sg) {
        const int nc = BT - sg;
        const bool act = idx < nc;
        const int li = idx, lj = idx + sg;
        const int ljc = lj < BT ? lj : BT - 1;
        const int i = t * BT + li, j = t * BT + lj;
        float ev = edge_min32(&dT[li][0], &dT[1][ljc]);
        float e1 = BIGV, opt0 = 0.f, x1 = BIGV, x2 = BIGV;
        if (act) {
            if (h == 0) {
                e1 = ev;
                opt0 = dT[li + 1][lj] + s_eunp[li];
            } else {
                x1 = dT[li][lj - 1] + s_eunp[lj];
                float pe = epm[li][lj];
                if (pe < BIGV) x2 = dT[li + 1][lj - 1] + pe;
            }
        }
        float y1 = __shfl_xor(x1, 1), y2 = __shfl_xor(x2, 1);
        if (act && h == 0) {
            float best = fminf(e1, y2);
            int cch = (best == opt0) ? 0 : (best == y1) ? 1
                     : (best == y2 && y2 < BIGV) ? 2 : 3;
            dT[li][lj] = best;
            dpG[(size_t)i * LSEQ + j] = best;
            if (i > 0) dpG[(size_t)j * LSEQ + i - 1] = best;
            choice_write(mask, mb + (size_t)j * LSEQ + i, cch, mmode);
        }
    }
}

// ---------- fused dispatch F_d: phases (2d-1, 2d) ----------
// Even block (I, J=I+2d): computes odd tiles (I,J-1) [curA] and (I+1,J) [curB]
// from global phase<=2d-2 data, sweeps them concurrently (waves 0,1), then the
// even tile from LDS. Writes: B always, A only block 0, E always (keeps all
// same-cacheline mirror/choice writers within one block). Update blocks
// pre-accumulate acc pairs m in {2d-3,2d-2} for future tiles.
__global__ __launch_bounds__(256) void fused_kernel(
    float* __restrict__ e_pair, const float* __restrict__ e_unp,
    void* mask, float* __restrict__ acc, int d)
{
    __shared__ float dgI[BT + 1][PIT], dgI1[BT + 1][PIT];
    __shared__ float dgJ1[BT + 1][PIT], dgJ[BT + 1][PIT];
    __shared__ float curA[BT + 1][PIT], curB[BT + 1][PIT], curE[BT + 1][PIT];
    __shared__ float part4[4][BT][PIT];
    __shared__ float epmA[BT][PIT], epmB[BT][PIT];
    __shared__ float browA[BT], bcolA[BT], browB[BT], bcolB[BT];
    __shared__ float browE[BT], bcolE[BT];
    __shared__ float eU_I[BT], eU_I1[BT], eU_J1[BT], eU_J[BT];
    __shared__ float s_bcA, s_bcB, s_bcE;

    const int nEven = (d <= 5) ? (NT - 2 * d) : 0;
    const int nOdd1 = (d == 6) ? 1 : 0;
    const int b = blockIdx.x % BATCH;
    const int u = blockIdx.x / BATCH;
    const int tid = threadIdx.x, lane = tid & 63, wv = tid >> 6;
    float* dpG = e_pair + (size_t)b * NN;
    const size_t mb = (size_t)b * NN;
    const int mmode = detect_mmode_wave((const unsigned char*)mask, lane);

    // ================= update role =================
    if (u >= nEven + nOdd1) {
        const int* ent = c_upd[c_updS[d] + (u - nEven - nOdd1)];
        const int sp = ent[0], It = ent[1], nM = ent[6], first = ent[7];
        int fm[4] = {ent[2], ent[3], ent[4], ent[5]};
        minplus_slot(dpG, It, It + sp, fm, nM, wv, 4, lane, part4[wv]);
        __syncthreads();
        float* accT = acc + ((size_t)(b * 36 + c_sb4[sp] + It) << 10);
        for (int z = tid; z < BT * BT; z += 256) {
            int li = z >> 5, lj = z & 31;
            float m = fminf(fminf(part4[0][li][lj], part4[1][li][lj]),
                            fminf(part4[2][li][lj], part4[3][li][lj]));
            accT[z] = first ? m : fminf(accT[z], m);
        }
        return;
    }

    // ================= odd-only role (d=6): tile (0,11) =================
    if (d == 6) {
        const int K = 0, so = 11, Jo = 11;
        for (int z = tid; z < BT * BT; z += 256) {
            int li = z >> 5, lj = z & 31;
            dgI[li][lj] = (lj >= li) ? dpG[(size_t)(K * BT + li) * LSEQ + K * BT + lj] : BIGV;
            dgJ1[li][lj] = (lj >= li) ? dpG[(size_t)(Jo * BT + li) * LSEQ + Jo * BT + lj] : BIGV;
            int i = K * BT + li, j = Jo * BT + lj;
            bool ok = (j - i > 4) && mask_read(mask, mb + (size_t)i * LSEQ + j, mmode);
            epmA[li][lj] = ok ? dpG[(size_t)i * LSEQ + j] : BIGV;
        }
        for (int z = tid; z < PIT; z += 256) {
            dgI[BT][z] = BIGV; dgJ1[BT][z] = BIGV; curA[BT][z] = BIGV;
        }
        if (tid < BT) {
            browA[tid] = dpG[(size_t)((K + 1) * BT) * LSEQ + Jo * BT + tid];
            eU_I[tid] = e_unp[b * LSEQ + K * BT + tid];
        } else if (tid < 2 * BT) {
            int q = tid - BT;
            bcolA[q] = dpG[(size_t)(K * BT + q) * LSEQ + Jo * BT - 1];
            eU_J1[q] = e_unp[b * LSEQ + Jo * BT + q];
        } else if (tid == 2 * BT) {
            s_bcA = dpG[(size_t)((K + 1) * BT) * LSEQ + Jo * BT - 1];
        }
        int fm[4]; int nfm = fresh_list(d, so, 1, K, fm);
        minplus_slot(dpG, K, Jo, fm, nfm, wv, 4, lane, part4[wv]);
        __syncthreads();
        const float* accT = acc + ((size_t)(b * 36 + c_sb4[so] + K) << 10);
        for (int z = tid; z < BT * BT; z += 256) {
            int li = z >> 5, lj = z & 31;
            float m = fminf(fminf(part4[0][li][lj], part4[1][li][lj]),
                            fminf(part4[2][li][lj], part4[3][li][lj]));
            curA[li][lj] = fminf(m, accT[z]);
        }
        __syncthreads();
        if (wv == 0)
            sweep_wave(dgI, dgJ1, curA, epmA, eU_I, eU_J1,
                       browA, bcolA, s_bcA, K, Jo, dpG, mb, mask, mmode, lane, 1);
        return;
    }

    // ================= even role: tiles A=(I,J-1), B=(I+1,J), E=(I,J) =================
    const int I = u, J = I + 2 * d, so = 2 * d - 1;

    // S0: stage diag tiles, epmA/epmB, e_unp, boundary rows/cols (all global, old)
    for (int z = tid; z < BT * BT; z += 256) {
        int li = z >> 5, lj = z & 31;
        bool up = (lj >= li);
        dgI[li][lj]  = up ? dpG[(size_t)(I * BT + li) * LSEQ + I * BT + lj] : BIGV;
        dgI1[li][lj] = up ? dpG[(size_t)((I + 1) * BT + li) * LSEQ + (I + 1) * BT + lj] : BIGV;
        dgJ1[li][lj] = up ? dpG[(size_t)((J - 1) * BT + li) * LSEQ + (J - 1) * BT + lj] : BIGV;
        dgJ[li][lj]  = up ? dpG[(size_t)(J * BT + li) * LSEQ + J * BT + lj] : BIGV;
    }
    for (int z = tid; z < BT * BT; z += 256) {
        int li = z >> 5, lj = z & 31;
        int iA = I * BT + li, jA = (J - 1) * BT + lj;
        bool okA = (jA - iA > 4) && mask_read(mask, mb + (size_t)iA * LSEQ + jA, mmode);
        epmA[li][lj] = okA ? dpG[(size_t)iA * LSEQ + jA] : BIGV;
        int iB = (I + 1) * BT + li, jB = J * BT + lj;
        bool okB = (jB - iB > 4) && mask_read(mask, mb + (size_t)iB * LSEQ + jB, mmode);
        epmB[li][lj] = okB ? dpG[(size_t)iB * LSEQ + jB] : BIGV;
    }
    for (int z = tid; z < PIT; z += 256) {
        dgI[BT][z] = BIGV; dgI1[BT][z] = BIGV; dgJ1[BT][z] = BIGV; dgJ[BT][z] = BIGV;
        curA[BT][z] = BIGV; curB[BT][z] = BIGV; curE[BT][z] = BIGV;
    }
    if (tid < BT) eU_I[tid] = e_unp[b * LSEQ + I * BT + tid];
    else if (tid < 2 * BT) eU_I1[tid - BT] = e_unp[b * LSEQ + (I + 1) * BT + (tid - BT)];
    else if (tid < 3 * BT) eU_J1[tid - 2 * BT] = e_unp[b * LSEQ + (J - 1) * BT + (tid - 2 * BT)];
    else if (tid < 4 * BT) eU_J[tid - 3 * BT] = e_unp[b * LSEQ + J * BT + (tid - 3 * BT)];
    else if (tid < 5 * BT) browA[tid - 4 * BT] = dpG[(size_t)((I + 1) * BT) * LSEQ + (J - 1) * BT + (tid - 4 * BT)];
    else if (tid < 6 * BT) bcolA[tid - 5 * BT] = dpG[(size_t)(I * BT + tid - 5 * BT) * LSEQ + (J - 1) * BT - 1];
    else if (tid < 7 * BT) browB[tid - 6 * BT] = dpG[(size_t)((I + 2) * BT) * LSEQ + J * BT + (tid - 6 * BT)];
    else browB[0] = browB[0], bcolB[tid - 7 * BT] = dpG[(size_t)((I + 1) * BT + tid - 7 * BT) * LSEQ + J * BT - 1];
    if (tid == 0) s_bcA = (so >= 2) ? dpG[(size_t)((I + 1) * BT) * LSEQ + (J - 1) * BT - 1] : BIGV;
    if (tid == 1) s_bcB = (so >= 2) ? dpG[(size_t)((I + 2) * BT) * LSEQ + J * BT - 1] : BIGV;
    if (tid == 2) s_bcE = dpG[(size_t)((I + 1) * BT) * LSEQ + J * BT - 1];

    int fmA[4], fmB[4], fmE[4];
    const int nfmA = fresh_list(d, so, 1, I, fmA);
    const int nfmB = fresh_list(d, so, 1, I + 1, fmB);
    const int nfmE = fresh_list(d, 2 * d, 0, I, fmE);
    __syncthreads();

    // S1: far-init fresh pairs for A (waves 0-1) and B (waves 2-3)
    if (so > 1) {
        if (wv < 2) minplus_slot(dpG, I, J - 1, fmA, nfmA, wv, 2, lane, part4[wv]);
        else        minplus_slot(dpG, I + 1, J, fmB, nfmB, wv - 2, 2, lane, part4[wv]);
    }
    __syncthreads();

    // S2: merge curA (tids 0-127) / curB (tids 128-255), + acc when span>=7
    {
        const int half = tid & 127;
        const bool lo = (tid < 128);
        float (*cur)[PIT] = lo ? curA : curB;
        const int K = lo ? I : I + 1;
        if (so == 1) {
            for (int z = half; z < BT * BT; z += 128) cur[z >> 5][z & 31] = BIGV;
        } else {
            const float* accT = (so >= 7)
                ? acc + ((size_t)(b * 36 + c_sb4[so] + K) << 10) : 0;
            const int p0 = lo ? 0 : 2, p1 = lo ? 1 : 3;
            for (int z = half; z < BT * BT; z += 128) {
                int li = z >> 5, lj = z & 31;
                float m = fminf(part4[p0][li][lj], part4[p1][li][lj]);
                if (accT) m = fminf(m, accT[z]);
                cur[li][lj] = m;
            }
        }
    }
    __syncthreads();

    // S3: concurrent sweeps A (wave 0, write iff I==0) and B (wave 1, write);
    //     waves 2-3 compute E's fresh-global pairs into part4[2],[3]
    if (wv == 0)
        sweep_wave(dgI, dgJ1, curA, epmA, eU_I, eU_J1, browA, bcolA, s_bcA,
                   I, J - 1, dpG, mb, mask, mmode, lane, I == 0);
    else if (wv == 1)
        sweep_wave(dgI1, dgJ, curB, epmB, eU_I1, eU_J, browB, bcolB, s_bcB,
                   I + 1, J, dpG, mb, mask, mmode, lane, 1);
    else
        minplus_slot(dpG, I, J, fmE, nfmE, wv - 2, 2, lane, part4[wv]);
    __syncthreads();

    // S4: LDS pairs (waves 0,1 -> part4[0],[1]); waves 2-3 restage epmE into
    //     epmA and copy browE/bcolE from curB/curA
    if (wv == 0)
        pair_via_curB(dpG, I, d, curA, curB, browB, lane, part4[0]);
    else if (wv == 1) {
        if (d >= 2) pair_via_curA(dpG, J, curA, lane, part4[1]);
        else for (int z = lane; z < BT * BT; z += 64) part4[1][z >> 5][z & 31] = BIGV;
    } else {
        const int half = tid - 128;
        for (int z = half; z < BT * BT; z += 128) {
            int li = z >> 5, lj = z & 31;
            int i = I * BT + li, j = J * BT + lj;
            bool ok = (j - i > 4) && mask_read(mask, mb + (size_t)i * LSEQ + j, mmode);
            epmA[li][lj] = ok ? dpG[(size_t)i * LSEQ + j] : BIGV;
        }
        if (half < BT) browE[half] = curB[0][half];
        else if (half < 2 * BT) bcolE[half - BT] = curA[half - BT][31];
    }
    __syncthreads();

    // S5: merge curE = min(pairs, fresh, acc for s>=8)
    {
        const float* accT = (2 * d >= 8)
            ? acc + ((size_t)(b * 36 + c_sb4[2 * d] + I) << 10) : 0;
        for (int z = tid; z < BT * BT; z += 256) {
            int li = z >> 5, lj = z & 31;
            float m = fminf(fminf(part4[0][li][lj], part4[1][li][lj]),
                            fminf(part4[2][li][lj], part4[3][li][lj]));
            if (accT) m = fminf(m, accT[z]);
            curE[li][lj] = m;
        }
    }
    __syncthreads();

    // S6: even sweep (wave 0, write)
    if (wv == 0)
        sweep_wave(dgI, dgJ, curE, epmA, eU_I, eU_J, browE, bcolE, s_bcE,
                   I, J, dpG, mb, mask, mmode, lane, 1);
}

// Traceback (R3/R6-proven): 8 waves stage choices into LDS, wave 0 traverses
// barrier-free with the interval cached in registers.
__global__ __launch_bounds__(512) void tb_kernel(
    const float* __restrict__ e_pair, const void* mask, float* __restrict__ out)
{
    const int b = blockIdx.x;
    const int tid = threadIdx.x;
    const int lane = tid & 63, wv = tid >> 6;
    const float* dp = e_pair + (size_t)b * NN;
    const size_t mb = (size_t)b * NN;
    const int mmode = detect_mmode_wave((const unsigned char*)mask, lane);

    __shared__ __align__(16) unsigned char ch[LSEQ * LSEQ];   // 147456 B
    __shared__ short res[LSEQ];
    __shared__ int st[TB_STK];

    if (mmode == 1) {
        const uint4* src = (const uint4*)((const unsigned char*)mask + mb);
        for (int z = tid; z < (int)(NN / 16); z += 512) ((uint4*)ch)[z] = src[z];
    } else if (mmode == 2) {
        const uint4* src = (const uint4*)((const unsigned char*)mask + mb * 2);
        for (int z = tid; z < (int)(NN / 8); z += 512) {
            uint4 v = src[z];
            unsigned int lo = (v.x & 0xFFu) | (((v.x >> 16) & 0xFFu) << 8)
                            | ((v.y & 0xFFu) << 16) | (((v.y >> 16) & 0xFFu) << 24);
            unsigned int hi = (v.z & 0xFFu) | (((v.z >> 16) & 0xFFu) << 8)
                            | ((v.w & 0xFFu) << 16) | (((v.w >> 16) & 0xFFu) << 24);
            ((unsigned int*)ch)[z * 2] = lo;
            ((unsigned int*)ch)[z * 2 + 1] = hi;
        }
    } else {
        const uint4* src = (const uint4*)((const unsigned char*)mask + mb * 4);
        for (int z = tid; z < (int)(NN / 4); z += 512) {
            uint4 v = src[z];
            ((unsigned int*)ch)[z] = (v.x & 0xFFu) | ((v.y & 0xFFu) << 8)
                                   | ((v.z & 0xFFu) << 16) | ((v.w & 0xFFu) << 24);
        }
    }
    for (int l = tid; l < LSEQ; l += 512) res[l] = -1;
    __syncthreads();
    if (wv != 0) return;   // wave 0 traverses alone

    int sp = 0;
    int ci = 0, cj = LSEQ - 1;
    int have = 1;
    for (int iter = 0; iter < 8192; ++iter) {
        if (!have) {
            if (sp == 0) break;
            --sp;
            int pk = st[sp];
            ci = pk >> 16; cj = pk & 0xFFFF;
        }
        have = 0;
        if (ci >= cj) continue;
        int c = ch[(size_t)cj * LSEQ + ci];
        if (c == 0) { ++ci; have = 1; }
        else if (c == 1) { --cj; have = 1; }
        else if (c == 2) {
            res[ci] = (short)cj; res[cj] = (short)ci;
            if (ci + 1 <= cj - 1) { ++ci; --cj; have = 1; }
        } else {
            const int d = cj - ci;
            const float* rowi = dp + (size_t)ci * LSEQ;
            const float* mrow = dp + (size_t)cj * LSEQ;
            float bv = BIGV; int bt = d;
            for (int t = lane; t < d; t += 64) {
                float cc = rowi[ci + t] + mrow[ci + t];
                if (cc < bv || (cc == bv && t < bt)) { bv = cc; bt = t; }
            }
            for (int m = 32; m > 0; m >>= 1) {
                float ov = __shfl_xor(bv, m, 64);
                int   ot = __shfl_xor(bt, m, 64);
                if (ov < bv || (ov == bv && ot < bt)) { bv = ov; bt = ot; }
            }
            int k = ci + bt;
            if (sp < TB_STK - 1) { st[sp] = ((k + 1) << 16) | cj; ++sp; }
            cj = k; have = 1;
        }
    }

    for (int l = lane; l < LSEQ; l += 64)
        out[b * LSEQ + l] = (float)res[l];
    if (lane == 0)
        out[BATCH * LSEQ + b] = dp[LSEQ - 1];
}

extern "C" void kernel_launch(void* const* d_in, const int* in_sizes, int n_in,
                              void* d_out, int out_size, void* d_ws, size_t ws_size,
                              hipStream_t stream) {
    float* e_pair = (float*)d_in[0];
    const float* e_unp = (const float*)d_in[1];
    void* mask = d_in[2];
    float* acc = (float*)d_ws;   // 32 x 36 x 1024 floats = 4.72 MB
    (void)ws_size;

    // blocks per fused dispatch: nEven + oddonly + updates
    static const int nblk[7] = {0, 10, 8, 15, 10, 3, 1};

    diag_kernel<<<BATCH * NT, 64, 0, stream>>>(e_pair, e_unp, mask);
    for (int d = 1; d <= 6; ++d)
        fused_kernel<<<BATCH * nblk[d], 256, 0, stream>>>(e_pair, e_unp, mask, acc, d);
    tb_kernel<<<BATCH, 512, 0, stream>>>(e_pair, mask, (float*)d_out);
}

// Round 11
// 776.741 us; speedup vs baseline: 1.5819x; 1.0467x over previous
//
#include <hip/hip_runtime.h>

#define LSEQ 384
#define BATCH 32
#define BIGV 1e30f
#define TB_STK 448
#define NN ((size_t)LSEQ * LSEQ)
#define BT 32          // tile size
#define NT 12          // tiles per side
#define PIT 33         // LDS pitch

__device__ __constant__ int c_sb4[12] = {0,0,0,0, 0, 8, 15, 21, 26, 30, 33, 35};

__device__ __forceinline__ int detect_mmode_wave(const unsigned char* m0, int lane) {
    unsigned char v = m0[lane & 63];
    unsigned long long big = __ballot(v >= 2);
    unsigned long long off = __ballot((((lane & 63) & 3) != 0) && (v != 0));
    return big ? 2 : (off ? 1 : 0);
}
__device__ __forceinline__ bool mask_read(const void* mask, size_t idx, int mmode) {
    if (mmode == 0) return ((const unsigned int*)mask)[idx] != 0;
    if (mmode == 1) return ((const unsigned char*)mask)[idx] != 0;
    return ((const unsigned short*)mask)[idx] != 0;
}
__device__ __forceinline__ void choice_write(void* mask, size_t idx, int c, int mmode) {
    if (mmode == 0) ((unsigned int*)mask)[idx] = (unsigned int)c;
    else if (mmode == 1) ((unsigned char*)mask)[idx] = (unsigned char)c;
    else ((unsigned short*)mask)[idx] = (unsigned short)c;
}

// Fixed-length branchless edge reduction (R2-verified): min over kk in [0,32)
// of rowp[kk] + colp[kk*PIT]; out-of-range terms >= 1e30 via BIGV prefill ->
// never win or tie -> bitwise identical to the ranged version.
__device__ __forceinline__ float edge_min32(const float* rowp, const float* colp) {
    float a0 = BIGV, a1 = BIGV, a2 = BIGV, a3 = BIGV;
    #pragma unroll
    for (int kk = 0; kk < 32; kk += 4) {
        float r0 = rowp[kk], r1 = rowp[kk + 1], r2 = rowp[kk + 2], r3 = rowp[kk + 3];
        const float* cb = colp + kk * PIT;
        float c0 = cb[0], c1 = cb[PIT], c2 = cb[2 * PIT], c3 = cb[3 * PIT];
        a0 = fminf(a0, r0 + c0); a1 = fminf(a1, r1 + c1);
        a2 = fminf(a2, r2 + c2); a3 = fminf(a3, r3 + c3);
    }
    return fminf(fminf(a0, a1), fminf(a2, a3));
}

// Min-plus of <=2 middle panels, 4-wave split (R6-verified, term-identical
// to R2's far-init): wave w handles M=fm[w>>1], kq range (w&1)*4..+3.
__device__ __forceinline__ void minplus_waves(
    const float* __restrict__ dpG, int I, int J, const int* fm, int nfm,
    int wv, int lane, float part[4][BT][PIT])
{
    const int r0 = (lane >> 3) << 2, c0 = (lane & 7) << 2;
    float r16[16];
    #pragma unroll
    for (int z = 0; z < 16; ++z) r16[z] = BIGV;
    const int mi = wv >> 1, kqB = (wv & 1) * 4;
    if (mi < nfm) {
        const int M = fm[mi];
        #pragma unroll
        for (int q = 0; q < 4; ++q) {
            const int k = M * BT + (kqB + q) * 4;
            float4 a0 = *(const float4*)&dpG[(size_t)(I * BT + r0 + 0) * LSEQ + k];
            float4 a1 = *(const float4*)&dpG[(size_t)(I * BT + r0 + 1) * LSEQ + k];
            float4 a2 = *(const float4*)&dpG[(size_t)(I * BT + r0 + 2) * LSEQ + k];
            float4 a3 = *(const float4*)&dpG[(size_t)(I * BT + r0 + 3) * LSEQ + k];
            float4 b0 = *(const float4*)&dpG[(size_t)(J * BT + c0 + 0) * LSEQ + k];
            float4 b1 = *(const float4*)&dpG[(size_t)(J * BT + c0 + 1) * LSEQ + k];
            float4 b2 = *(const float4*)&dpG[(size_t)(J * BT + c0 + 2) * LSEQ + k];
            float4 b3 = *(const float4*)&dpG[(size_t)(J * BT + c0 + 3) * LSEQ + k];
            #pragma unroll
            for (int ri = 0; ri < 4; ++ri) {
                float4 av = ri == 0 ? a0 : ri == 1 ? a1 : ri == 2 ? a2 : a3;
                #pragma unroll
                for (int ci = 0; ci < 4; ++ci) {
                    float4 bv = ci == 0 ? b0 : ci == 1 ? b1 : ci == 2 ? b2 : b3;
                    float m = fminf(fminf(av.x + bv.x, av.y + bv.y),
                                    fminf(av.z + bv.z, av.w + bv.w));
                    r16[ri * 4 + ci] = fminf(r16[ri * 4 + ci], m);
                }
            }
        }
    }
    #pragma unroll
    for (int ri = 0; ri < 4; ++ri)
        #pragma unroll
        for (int ci = 0; ci < 4; ++ci)
            part[wv][r0 + ri][c0 + ci] = r16[ri * 4 + ci];
}

// R2/R6-verified diag in-tile sweep (one wave). Global writes gated: within
// the fused dispatch, row-tile t's mask/dp lines have ONE writer block.
__device__ void diag_sweep(float (*dT)[PIT], const float (*epm)[PIT],
                           const float* eunp, int t, float* __restrict__ dpG,
                           size_t mb, void* mask, int mmode, int lane, int dowrite)
{
    const int idx = lane >> 1, h = lane & 1;
    for (int sg = 1; sg < BT; ++sg) {
        const int nc = BT - sg;
        const bool act = idx < nc;
        const int li = idx, lj = idx + sg;
        const int ljc = lj < BT ? lj : BT - 1;
        const int i = t * BT + li, j = t * BT + lj;
        float ev = edge_min32(&dT[li][0], &dT[1][ljc]);
        float e1 = BIGV, opt0 = 0.f, x1 = BIGV, x2 = BIGV;
        if (act) {
            if (h == 0) {
                e1 = ev;                           // includes opt0(kk=li), opt1(kk=lj-1)
                opt0 = dT[li + 1][lj] + eunp[li];
            } else {
                x1 = dT[li][lj - 1] + eunp[lj];
                float pe = epm[li][lj];
                if (pe < BIGV) x2 = dT[li + 1][lj - 1] + pe;
            }
        }
        float y1 = __shfl_xor(x1, 1), y2 = __shfl_xor(x2, 1);
        if (act && h == 0) {
            float best = fminf(e1, y2);
            int cch = (best == opt0) ? 0 : (best == y1) ? 1
                     : (best == y2 && y2 < BIGV) ? 2 : 3;
            dT[li][lj] = best;
            if (dowrite) {
                dpG[(size_t)i * LSEQ + j] = best;
                if (i > 0) dpG[(size_t)j * LSEQ + i - 1] = best;
                choice_write(mask, mb + (size_t)j * LSEQ + i, cch, mmode);
            }
        }
    }
}

// R2-verified off-diag in-tile sweep (one wave), from R10 (validated).
__device__ void sweep_wave(
    const float (*dTI)[PIT], const float (*dTJ)[PIT], float (*cur)[PIT],
    const float (*epm)[PIT], const float* eI, const float* eJ,
    const float* brow, const float* bcol, float bcorn,
    int I, int J, float* __restrict__ dpG, size_t mb, void* mask, int mmode,
    int lane)
{
    const int idx = lane >> 1, h = lane & 1;
    for (int sg = -(BT - 1); sg <= BT - 1; ++sg) {
        const int asg = sg < 0 ? -sg : sg;
        const int nc = BT - asg;
        const bool act = idx < nc;
        const int li = (sg >= 0) ? idx : idx - sg;
        const int lj = li + sg;
        const int lic = li < BT ? li : BT - 1;
        const int ljc = (lj < BT ? (lj >= 0 ? lj : 0) : BT - 1);
        const int i = I * BT + li, j = J * BT + lj;
        const float* rowp = (h == 0) ? &dTI[lic][0] : &cur[lic][0];
        const float* colp = (h == 0) ? &cur[1][ljc] : &dTJ[1][ljc];
        float ev = edge_min32(rowp, colp);
        float e1 = BIGV, opt0 = 0.f, farv = BIGV;
        float x0 = BIGV, x1 = BIGV, x2 = BIGV;
        if (act) {
            if (h == 0) {
                e1 = fminf(ev, dTI[li][BT - 1] + brow[lj]);
                opt0 = ((li + 1 < BT) ? cur[li + 1][lj] : brow[lj]) + eI[li];
                farv = cur[li][lj];
            } else {
                x0 = ev;
                x1 = ((lj >= 1) ? cur[li][lj - 1] : bcol[li]) + eJ[lj];
                float pe = epm[li][lj];
                if (pe < BIGV) {
                    float inner = (li + 1 < BT)
                        ? ((lj >= 1) ? cur[li + 1][lj - 1] : bcol[li + 1])
                        : ((lj >= 1) ? brow[lj - 1] : bcorn);
                    x2 = inner + pe;
                }
            }
        }
        float y0 = __shfl_xor(x0, 1), y1 = __shfl_xor(x1, 1), y2 = __shfl_xor(x2, 1);
        if (act && h == 0) {
            float best = fminf(fminf(fminf(e1, y0), farv), y2);
            int cch = (best == opt0) ? 0 : (best == y1) ? 1
                     : (best == y2 && y2 < BIGV) ? 2 : 3;
            cur[li][lj] = best;
            dpG[(size_t)i * LSEQ + j] = best;
            if (i > 0) dpG[(size_t)j * LSEQ + i - 1] = best;
            choice_write(mask, mb + (size_t)j * LSEQ + i, cch, mmode);
        }
    }
}

// ---------- fused dispatch 1: diag tiles + span-1 tiles, one block per pair.
// Block (b,I), I=0..10: waves 0/1 concurrently sweep diag tiles I, I+1 in
// LDS, then wave 0 sweeps (I,I+1) using brow/bcol from LDS. Ownership: block
// I writes diag I+1 (+ diag 0 for I==0) and span (I,I+1) -> every dp/mask
// row-tile has exactly one writer block (no cross-block cache-line sharing).
__global__ __launch_bounds__(256) void fused_d1_kernel(
    float* __restrict__ e_pair, const float* __restrict__ e_unp, void* mask)
{
    __shared__ float dA[BT + 1][PIT], dB[BT + 1][PIT], cur[BT + 1][PIT];
    __shared__ float epmA[BT][PIT], epmB[BT][PIT], epmS[BT][PIT];
    __shared__ float eA[BT], eB[BT], brow[BT], bcol[BT];

    const int b = blockIdx.x % BATCH;
    const int I = blockIdx.x / BATCH;          // 0..10
    const int tid = threadIdx.x, lane = tid & 63, wv = tid >> 6;
    float* dpG = e_pair + (size_t)b * NN;
    const size_t mb = (size_t)b * NN;
    const int mmode = detect_mmode_wave((const unsigned char*)mask, lane);

    for (int z = tid; z < (BT + 1) * PIT; z += 256) {
        ((float*)dA)[z] = BIGV; ((float*)dB)[z] = BIGV; ((float*)cur)[z] = BIGV;
    }
    if (tid < BT) eA[tid] = e_unp[b * LSEQ + I * BT + tid];
    else if (tid < 2 * BT) eB[tid - BT] = e_unp[b * LSEQ + (I + 1) * BT + (tid - BT)];
    __syncthreads();

    // diagonal entries + mirrors (ownership-gated)
    if (tid < BT) {
        int i = I * BT + tid;
        float v = eA[tid];
        dA[tid][tid] = v;
        if (I == 0) {
            dpG[(size_t)i * LSEQ + i] = v;
            if (i > 0) dpG[(size_t)i * LSEQ + i - 1] = v;
        }
    } else if (tid < 2 * BT) {
        int q = tid - BT, i = (I + 1) * BT + q;
        float v = eB[q];
        dB[q][q] = v;
        dpG[(size_t)i * LSEQ + i] = v;
        dpG[(size_t)i * LSEQ + i - 1] = v;     // i >= 32 > 0 always
    }
    // masked pair energies for tiles (I,I), (I+1,I+1), (I,I+1); dp load is
    // unconditional (breaks mask->load dependence)
    for (int z = tid; z < BT * BT; z += 256) {
        int li = z >> 5, lj = z & 31;
        {
            int i = I * BT + li, j = I * BT + lj;
            float pv = dpG[(size_t)i * LSEQ + j];
            bool ok = (lj - li > 4) && mask_read(mask, mb + (size_t)i * LSEQ + j, mmode);
            epmA[li][lj] = ok ? pv : BIGV;
        }
        {
            int i = (I + 1) * BT + li, j = (I + 1) * BT + lj;
            float pv = dpG[(size_t)i * LSEQ + j];
            bool ok = (lj - li > 4) && mask_read(mask, mb + (size_t)i * LSEQ + j, mmode);
            epmB[li][lj] = ok ? pv : BIGV;
        }
        {
            int i = I * BT + li, j = (I + 1) * BT + lj;
            float pv = dpG[(size_t)i * LSEQ + j];
            bool ok = (j - i > 4) && mask_read(mask, mb + (size_t)i * LSEQ + j, mmode);
            epmS[li][lj] = ok ? pv : BIGV;
        }
    }
    __syncthreads();

    if (wv == 0)      diag_sweep(dA, epmA, eA, I, dpG, mb, mask, mmode, lane, I == 0);
    else if (wv == 1) diag_sweep(dB, epmB, eB, I + 1, dpG, mb, mask, mmode, lane, 1);
    __syncthreads();

    if (tid < BT) brow[tid] = dB[0][tid];          // dp[(I+1)*32][J*32+lj]
    else if (tid < 2 * BT) bcol[tid - BT] = dA[tid - BT][BT - 1];  // dp[i][J*32-1]
    __syncthreads();

    if (wv == 0)
        sweep_wave(dA, dB, cur, epmS, eA, eB, brow, bcol, BIGV,
                   I, I + 1, dpG, mb, mask, mmode, lane);
}

// ---------- dispatches p=2..11 (R6-proven, + unconditional epm load) ----------
__global__ __launch_bounds__(256) void step_kernel(
    float* __restrict__ e_pair, const float* __restrict__ e_unp,
    void* mask, float* __restrict__ acc, int p)
{
    __shared__ float dTI[BT + 1][PIT], dTJ[BT + 1][PIT];
    __shared__ float cur[BT + 1][PIT];
    __shared__ float epm[BT][PIT];
    __shared__ float part[4][BT][PIT];
    __shared__ float brow[BT], bcol[BT], s_eI[BT], s_eJ[BT];
    __shared__ float bcorn;

    const int b = blockIdx.x % BATCH;
    const int u = blockIdx.x / BATCH;
    const int nswp = NT - p;
    const int tid = threadIdx.x, lane = tid & 63, wv = tid >> 6;
    float* dpG = e_pair + (size_t)b * NN;
    const size_t mb = (size_t)b * NN;

    if (u >= nswp) {
        // update role: pre-accumulate far-init pairs for future tiles
        int e = u - nswp, s2 = p + 1;
        while (s2 < NT && e >= NT - s2) { e -= NT - s2; ++s2; }
        const int I = e, J = I + s2;
        int fm[2]; fm[0] = I + p - 1; int nfm = 1;
        if (J - (p - 1) != fm[0]) fm[nfm++] = J - (p - 1);
        minplus_waves(dpG, I, J, fm, nfm, wv, lane, part);
        __syncthreads();
        float* accT = acc + ((size_t)(b * 36 + c_sb4[s2] + I) << 10);
        const bool first = (p == (s2 + 1) / 2 + 1);
        for (int z = tid; z < BT * BT; z += 256) {
            int li = z >> 5, lj = z & 31;
            float m = fminf(fminf(part[0][li][lj], part[1][li][lj]),
                            fminf(part[2][li][lj], part[3][li][lj]));
            accT[z] = first ? m : fminf(accT[z], m);
        }
        return;
    }

    // sweep role: tile (I, J = I+p)
    const int I = u, J = I + p, s = p;
    const int mmode = detect_mmode_wave((const unsigned char*)mask, lane);

    for (int z = tid; z < BT * BT; z += 256) {
        int li = z >> 5, lj = z & 31;
        dTI[li][lj] = (lj >= li) ? dpG[(size_t)(I * BT + li) * LSEQ + I * BT + lj] : BIGV;
        dTJ[li][lj] = (lj >= li) ? dpG[(size_t)(J * BT + li) * LSEQ + J * BT + lj] : BIGV;
    }
    for (int z = tid; z < PIT; z += 256) {
        dTI[BT][z] = BIGV; dTJ[BT][z] = BIGV; cur[BT][z] = BIGV;
    }
    if (tid < BT) {
        brow[tid] = dpG[(size_t)((I + 1) * BT) * LSEQ + J * BT + tid];
        s_eI[tid] = e_unp[b * LSEQ + I * BT + tid];
    } else if (tid < 2 * BT) {
        int q = tid - BT;
        bcol[q] = dpG[(size_t)(I * BT + q) * LSEQ + J * BT - 1];
        s_eJ[q] = e_unp[b * LSEQ + J * BT + q];
    } else if (tid == 2 * BT) {
        bcorn = (s >= 2) ? dpG[(size_t)((I + 1) * BT) * LSEQ + J * BT - 1] : BIGV;
    }
    for (int z = tid; z < BT * BT; z += 256) {
        int li = z >> 5, lj = z & 31;
        int i = I * BT + li, j = J * BT + lj;
        float pv = dpG[(size_t)i * LSEQ + j];      // unconditional: no dep on mask
        bool ok = (j - i > 4) && mask_read(mask, mb + (size_t)i * LSEQ + j, mmode);
        epm[li][lj] = ok ? pv : BIGV;
    }

    int fm[2]; int nfm = 0;
    if (s >= 2) fm[nfm++] = I + 1;
    if (s >= 3) fm[nfm++] = J - 1;
    minplus_waves(dpG, I, J, fm, nfm, wv, lane, part);
    __syncthreads();

    const float* accT = acc + ((size_t)(b * 36 + c_sb4[s] + I) << 10);
    for (int z = tid; z < BT * BT; z += 256) {
        int li = z >> 5, lj = z & 31;
        float m = fminf(fminf(part[0][li][lj], part[1][li][lj]),
                        fminf(part[2][li][lj], part[3][li][lj]));
        if (s >= 4) m = fminf(m, accT[z]);
        cur[li][lj] = m;
    }
    __syncthreads();
    if (wv != 0) return;

    sweep_wave(dTI, dTJ, cur, epm, s_eI, s_eJ, brow, bcol, bcorn,
               I, J, dpG, mb, mask, mmode, lane);
}

// Traceback (R3/R6-proven traversal). Staging copies ONLY the lower triangle
// (choices live at [j][i], i<j) with vectorized per-row chunks -> ~half bytes.
__global__ __launch_bounds__(512) void tb_kernel(
    const float* __restrict__ e_pair, const void* mask, float* __restrict__ out)
{
    const int b = blockIdx.x;
    const int tid = threadIdx.x;
    const int lane = tid & 63, wv = tid >> 6;
    const float* dp = e_pair + (size_t)b * NN;
    const size_t mb = (size_t)b * NN;
    const int mmode = detect_mmode_wave((const unsigned char*)mask, lane);

    __shared__ __align__(16) unsigned char ch[LSEQ * LSEQ];   // full layout
    __shared__ short res[LSEQ];
    __shared__ int st[TB_STK];

    if (mmode == 1) {
        for (int j = wv; j < LSEQ; j += 8) {
            const uint4* src = (const uint4*)((const unsigned char*)mask + mb + (size_t)j * LSEQ);
            uint4* dst = (uint4*)(ch + (size_t)j * LSEQ);
            const int nch = (j + 15) >> 4;
            for (int c = lane; c < nch; c += 64) dst[c] = src[c];
        }
    } else if (mmode == 2) {
        for (int j = wv; j < LSEQ; j += 8) {
            const uint4* src = (const uint4*)((const unsigned short*)mask + mb + (size_t)j * LSEQ);
            uint4* dst = (uint4*)(ch + (size_t)j * LSEQ);
            const int nch = (j + 15) >> 4;
            for (int c = lane; c < nch; c += 64) {
                uint4 v0 = src[2 * c], v1 = src[2 * c + 1];
                uint4 o;
                o.x = (v0.x & 0xFFu) | (((v0.x >> 16) & 0xFFu) << 8)
                    | ((v0.y & 0xFFu) << 16) | (((v0.y >> 16) & 0xFFu) << 24);
                o.y = (v0.z & 0xFFu) | (((v0.z >> 16) & 0xFFu) << 8)
                    | ((v0.w & 0xFFu) << 16) | (((v0.w >> 16) & 0xFFu) << 24);
                o.z = (v1.x & 0xFFu) | (((v1.x >> 16) & 0xFFu) << 8)
                    | ((v1.y & 0xFFu) << 16) | (((v1.y >> 16) & 0xFFu) << 24);
                o.w = (v1.z & 0xFFu) | (((v1.z >> 16) & 0xFFu) << 8)
                    | ((v1.w & 0xFFu) << 16) | (((v1.w >> 16) & 0xFFu) << 24);
                dst[c] = o;
            }
        }
    } else {
        for (int j = wv; j < LSEQ; j += 8) {
            const uint4* src = (const uint4*)((const unsigned int*)mask + mb + (size_t)j * LSEQ);
            uint4* dst = (uint4*)(ch + (size_t)j * LSEQ);
            const int nch = (j + 15) >> 4;
            for (int c = lane; c < nch; c += 64) {
                uint4 s0 = src[4 * c], s1 = src[4 * c + 1], s2 = src[4 * c + 2], s3 = src[4 * c + 3];
                uint4 o;
                o.x = (s0.x & 0xFFu) | ((s0.y & 0xFFu) << 8) | ((s0.z & 0xFFu) << 16) | ((s0.w & 0xFFu) << 24);
                o.y = (s1.x & 0xFFu) | ((s1.y & 0xFFu) << 8) | ((s1.z & 0xFFu) << 16) | ((s1.w & 0xFFu) << 24);
                o.z = (s2.x & 0xFFu) | ((s2.y & 0xFFu) << 8) | ((s2.z & 0xFFu) << 16) | ((s2.w & 0xFFu) << 24);
                o.w = (s3.x & 0xFFu) | ((s3.y & 0xFFu) << 8) | ((s3.z & 0xFFu) << 16) | ((s3.w & 0xFFu) << 24);
                dst[c] = o;
            }
        }
    }
    for (int l = tid; l < LSEQ; l += 512) res[l] = -1;
    __syncthreads();
    if (wv != 0) return;   // wave 0 traverses alone

    int sp = 0;
    int ci = 0, cj = LSEQ - 1;
    int have = 1;
    for (int iter = 0; iter < 8192; ++iter) {
        if (!have) {
            if (sp == 0) break;
            --sp;
            int pk = st[sp];
            ci = pk >> 16; cj = pk & 0xFFFF;
        }
        have = 0;
        if (ci >= cj) continue;
        int c = ch[(size_t)cj * LSEQ + ci];
        if (c == 0) { ++ci; have = 1; }
        else if (c == 1) { --cj; have = 1; }
        else if (c == 2) {
            res[ci] = (short)cj; res[cj] = (short)ci;
            if (ci + 1 <= cj - 1) { ++ci; --cj; have = 1; }
        } else {
            const int d = cj - ci;
            const float* rowi = dp + (size_t)ci * LSEQ;
            const float* mrow = dp + (size_t)cj * LSEQ;
            float bv = BIGV; int bt = d;
            for (int t = lane; t < d; t += 64) {
                float cc = rowi[ci + t] + mrow[ci + t];
                if (cc < bv || (cc == bv && t < bt)) { bv = cc; bt = t; }
            }
            for (int m = 32; m > 0; m >>= 1) {
                float ov = __shfl_xor(bv, m, 64);
                int   ot = __shfl_xor(bt, m, 64);
                if (ov < bv || (ov == bv && ot < bt)) { bv = ov; bt = ot; }
            }
            int k = ci + bt;
            if (sp < TB_STK - 1) { st[sp] = ((k + 1) << 16) | cj; ++sp; }
            cj = k; have = 1;
        }
    }

    for (int l = lane; l < LSEQ; l += 64)
        out[b * LSEQ + l] = (float)res[l];
    if (lane == 0)
        out[BATCH * LSEQ + b] = dp[LSEQ - 1];
}

extern "C" void kernel_launch(void* const* d_in, const int* in_sizes, int n_in,
                              void* d_out, int out_size, void* d_ws, size_t ws_size,
                              hipStream_t stream) {
    float* e_pair = (float*)d_in[0];
    const float* e_unp = (const float*)d_in[1];
    void* mask = d_in[2];
    float* acc = (float*)d_ws;   // 32 x 36 x 1024 floats = 4.72 MB
    (void)ws_size;

    // update-block counts per dispatch p: tiles with p+1 <= s <= min(2p-2,11)
    static const int updC[12] = {0, 0, 0, 8, 13, 15, 14, 10, 6, 3, 1, 0};

    fused_d1_kernel<<<BATCH * (NT - 1), 256, 0, stream>>>(e_pair, e_unp, mask);
    for (int p = 2; p < NT; ++p)
        step_kernel<<<BATCH * (NT - p + updC[p]), 256, 0, stream>>>(
            e_pair, e_unp, mask, acc, p);
    tb_kernel<<<BATCH, 512, 0, stream>>>(e_pair, mask, (float*)d_out);
}